// Round 3
// baseline (28267.548 us; speedup 1.0000x reference)
//
#include <hip/hip_runtime.h>
#include <math.h>

// Problem constants
#define TT 256
#define BB 32
#define VV 4712
#define HH 500
#define FOURH 2000
#define MPRE 8160          // 255*32
#define NBLK_REC 250

// ---------------- workspace layout (float offsets) ----------------
// logits   : 0            .. 38,449,920   (8160*4712)
//   enc_pre: 0            .. 16,320,000   overlaps logits
//   dec_pre: 16,320,000   .. 32,640,000   overlaps logits
//   flags   : 33,000,000  (real barrier; dead region during lstm_rec)
//   abl flags: 200,000 / 210,000 (ablation barriers; logits dead after loss_rows,
//                                 re-zeroed by mid-stream memset before use)
// dec_h    : 38,449,920   .. 42,529,920   (8160*500)
// h_a      : 42,529,920   .. 42,545,920   (32*500, [u][b] layout)
// h_b      : 42,545,920   .. 42,561,920
// nll      : 42,561,920   .. 42,570,112   (8192)

#define OFF_DECPRE 16320000
#define OFF_FLAGS  33000000
#define OFF_ABL1   200000
#define OFF_ABL2   210000
#define OFF_DECH   38449920
#define OFF_HA     42529920
#define OFF_HB     42545920
#define OFF_NLL    42561920

// ---------------- generic fp32 tiled GEMM (unchanged) ----------------
__global__ __launch_bounds__(256) void gemm128(
    const float* __restrict__ A, int lda, int rowmap,
    const float* __restrict__ W,
    const float* __restrict__ b0, const float* __restrict__ b1,
    float* __restrict__ C, int ldc, int M, int N, int K) {
  __shared__ __align__(16) float As[16][132];
  __shared__ __align__(16) float Ws[16][132];
  const int tid = threadIdx.x;
  const int tx = tid & 15, ty = tid >> 4;
  const int m0 = blockIdx.x * 128, n0 = blockIdx.y * 128;

  float acc[2][2][4][4];
#pragma unroll
  for (int a = 0; a < 2; ++a)
#pragma unroll
    for (int b = 0; b < 2; ++b)
#pragma unroll
      for (int i = 0; i < 4; ++i)
#pragma unroll
        for (int j = 0; j < 4; ++j) acc[a][b][i][j] = 0.0f;

  const int srow = tid >> 2, kq0 = tid & 3;
  long arow[2];
  long wrow[2];
#pragma unroll
  for (int h = 0; h < 2; ++h) {
    int m = m0 + srow + h * 64;
    if (m >= M) m = M - 1;
    int rm = m;
    if (rowmap == 1) { int t = m >> 5, b = m & 31; rm = ((255 - t) << 5) + b; }
    arow[h] = (long)rm * lda;
    int n = n0 + srow + h * 64;
    if (n >= N) n = N - 1;
    wrow[h] = (long)n * K;
  }

  const int KT = (K + 15) >> 4;
  for (int kt = 0; kt < KT; ++kt) {
    const int kbase = kt * 16 + kq0 * 4;
    const bool kok = (kbase < K);
#pragma unroll
    for (int h = 0; h < 2; ++h) {
      float4 av = make_float4(0.f, 0.f, 0.f, 0.f);
      float4 wv = make_float4(0.f, 0.f, 0.f, 0.f);
      if (kok) {
        av = *(const float4*)&A[arow[h] + kbase];
        wv = *(const float4*)&W[wrow[h] + kbase];
      }
      const int ml = srow + h * 64;
      As[kq0 * 4 + 0][ml] = av.x; As[kq0 * 4 + 1][ml] = av.y;
      As[kq0 * 4 + 2][ml] = av.z; As[kq0 * 4 + 3][ml] = av.w;
      Ws[kq0 * 4 + 0][ml] = wv.x; Ws[kq0 * 4 + 1][ml] = wv.y;
      Ws[kq0 * 4 + 2][ml] = wv.z; Ws[kq0 * 4 + 3][ml] = wv.w;
    }
    __syncthreads();
#pragma unroll
    for (int k = 0; k < 16; ++k) {
      const float4 a0 = *(const float4*)&As[k][ty << 2];
      const float4 a1 = *(const float4*)&As[k][64 + (ty << 2)];
      const float4 w0 = *(const float4*)&Ws[k][tx << 2];
      const float4 w1 = *(const float4*)&Ws[k][64 + (tx << 2)];
      const float am[2][4] = {{a0.x, a0.y, a0.z, a0.w}, {a1.x, a1.y, a1.z, a1.w}};
      const float wn[2][4] = {{w0.x, w0.y, w0.z, w0.w}, {w1.x, w1.y, w1.z, w1.w}};
#pragma unroll
      for (int mh = 0; mh < 2; ++mh)
#pragma unroll
        for (int nh = 0; nh < 2; ++nh)
#pragma unroll
          for (int i = 0; i < 4; ++i)
#pragma unroll
            for (int j = 0; j < 4; ++j)
              acc[mh][nh][i][j] += am[mh][i] * wn[nh][j];
    }
    __syncthreads();
  }

  float4 biasv[2];
#pragma unroll
  for (int nh = 0; nh < 2; ++nh) {
    const int n = n0 + nh * 64 + (tx << 2);
    biasv[nh] = make_float4(0.f, 0.f, 0.f, 0.f);
    if (n < N) {
      if (b0) {
        float4 v = *(const float4*)&b0[n];
        biasv[nh].x += v.x; biasv[nh].y += v.y; biasv[nh].z += v.z; biasv[nh].w += v.w;
      }
      if (b1) {
        float4 v = *(const float4*)&b1[n];
        biasv[nh].x += v.x; biasv[nh].y += v.y; biasv[nh].z += v.z; biasv[nh].w += v.w;
      }
    }
  }
#pragma unroll
  for (int mh = 0; mh < 2; ++mh)
#pragma unroll
    for (int i = 0; i < 4; ++i) {
      const int m = m0 + mh * 64 + (ty << 2) + i;
      if (m < M) {
        float* crow = C + (long)m * ldc;
#pragma unroll
        for (int nh = 0; nh < 2; ++nh) {
          const int n = n0 + nh * 64 + (tx << 2);
          if (n < N) {
            float4 o;
            o.x = acc[mh][nh][i][0] + biasv[nh].x;
            o.y = acc[mh][nh][i][1] + biasv[nh].y;
            o.z = acc[mh][nh][i][2] + biasv[nh].z;
            o.w = acc[mh][nh][i][3] + biasv[nh].w;
            *(float4*)&crow[n] = o;
          }
        }
      }
    }
}

// ---------------- grid barrier v3: relaxed polls, ONE acquire fence per step ----
// Arrival: release store to own 128B-strided slot (single wbl2, orders h stores).
// Block 0 gathers all 250 flags with RELAXED sc1 loads (no buffer_inv per poll!),
// then release-stores gen. Others poll gen RELAXED. One acquire fence at exit
// makes prior remote writes (h) visible. This removes the per-poll-iteration
// full-L2-invalidate storm that r1/r2 theory-misses point to.
__device__ __forceinline__ void gbar3(unsigned* __restrict__ flags,
                                      unsigned* __restrict__ gen, unsigned step) {
  __syncthreads();
  if (threadIdx.x == 0) {
    __hip_atomic_store(&flags[blockIdx.x * 32], step, __ATOMIC_RELEASE,
                       __HIP_MEMORY_SCOPE_AGENT);
  }
  if (blockIdx.x == 0) {
    if (threadIdx.x < NBLK_REC) {
      while (__hip_atomic_load(&flags[threadIdx.x * 32], __ATOMIC_RELAXED,
                               __HIP_MEMORY_SCOPE_AGENT) < step) {
        __builtin_amdgcn_s_sleep(1);
      }
    }
    __syncthreads();
    if (threadIdx.x == 0) {
      __hip_atomic_store(gen, step, __ATOMIC_RELEASE, __HIP_MEMORY_SCOPE_AGENT);
    }
  } else if (threadIdx.x == 0) {
    while (__hip_atomic_load(gen, __ATOMIC_RELAXED,
                             __HIP_MEMORY_SCOPE_AGENT) < step) {
      __builtin_amdgcn_s_sleep(1);
    }
  }
  __syncthreads();
  __builtin_amdgcn_fence(__ATOMIC_ACQUIRE, "agent");
}

// ---------------- persistent LSTM recurrence (same structure as r2, gbar3) ----
__global__ __launch_bounds__(256) void lstm_rec(
    const float* __restrict__ enc_pre, const float* __restrict__ dec_pre,
    const float* __restrict__ enc_Whh, const float* __restrict__ dec_Whh,
    float* __restrict__ h_a, float* __restrict__ h_b,
    float* __restrict__ dec_h, unsigned* __restrict__ flags) {
  __shared__ __align__(16) float hs[512 * 32];
  __shared__ __align__(16) float wsl[512 * 8];
  __shared__ __align__(16) float redb[16 * 16 * 16];

  unsigned* gen = flags + 8192;
  const int tid = threadIdx.x;
  const int ks = tid >> 4;
  const int tm = (tid & 15) >> 1;
  const int tn = tid & 1;
  const int u0 = blockIdx.x * 2;

  const int v2 = tid & 15, pos2 = tid >> 4;
  const int row = ((pos2 & 1) << 2) + (v2 >> 2);
  const int bb  = ((pos2 >> 1) << 2) + (v2 & 3);
  const int gate = row & 3, ul = row >> 2;
  const int jglob = gate * 500 + u0 + ul;

  if (tid < 384) hs[16000 + tid] = 0.0f;

  float creg = 0.0f;

  const float* pres[2] = {enc_pre, dec_pre};
  const float* whhs[2] = {enc_Whh, dec_Whh};
  float* hcur = h_a;
  float* hnxt = h_b;
  unsigned step = 0;

  for (int ph = 0; ph < 2; ++ph) {
    const float* pre = pres[ph];
    const float* Whh = whhs[ph];
    __syncthreads();
    for (int c = tid; c < 1024; c += 256) {
      const int r = c & 7, kq = c >> 3;
      const int k = kq << 2;
      float4 v = make_float4(0.f, 0.f, 0.f, 0.f);
      if (k < 500) {
        const int j = (r & 3) * 500 + u0 + (r >> 2);
        v = *(const float4*)&Whh[j * 500 + k];
      }
      wsl[(k + 0) * 8 + r] = v.x;
      wsl[(k + 1) * 8 + r] = v.y;
      wsl[(k + 2) * 8 + r] = v.z;
      wsl[(k + 3) * 8 + r] = v.w;
    }
    __syncthreads();

    for (int t = 0; t < 255; ++t) {
      const float preval = pre[(t * 32 + bb) * 2000 + jglob];

      for (int c = tid; c < 4000; c += 256) {
        *(float4*)&hs[c * 4] = *(const float4*)&hcur[c * 4];
      }
      __syncthreads();

      float acc[4][4];
#pragma unroll
      for (int a = 0; a < 4; ++a)
#pragma unroll
        for (int b = 0; b < 4; ++b) acc[a][b] = 0.0f;

#pragma unroll
      for (int jj = 0; jj < 32; ++jj) {
        const int kl = (jj << 4) + ks;
        const float4 h4 = *(const float4*)&hs[kl * 32 + (tm << 2)];
        const float4 w4 = *(const float4*)&wsl[kl * 8 + (tn << 2)];
        acc[0][0] += w4.x * h4.x; acc[0][1] += w4.x * h4.y; acc[0][2] += w4.x * h4.z; acc[0][3] += w4.x * h4.w;
        acc[1][0] += w4.y * h4.x; acc[1][1] += w4.y * h4.y; acc[1][2] += w4.y * h4.z; acc[1][3] += w4.y * h4.w;
        acc[2][0] += w4.z * h4.x; acc[2][1] += w4.z * h4.y; acc[2][2] += w4.z * h4.z; acc[2][3] += w4.z * h4.w;
        acc[3][0] += w4.w * h4.x; acc[3][1] += w4.w * h4.y; acc[3][2] += w4.w * h4.z; acc[3][3] += w4.w * h4.w;
      }

      const int pos = (tm << 1) | tn;
#pragma unroll
      for (int r = 0; r < 4; ++r) {
        float4 v = make_float4(acc[r][0], acc[r][1], acc[r][2], acc[r][3]);
        *(float4*)&redb[((ks << 4) + pos) * 16 + (r << 2)] = v;
      }
      __syncthreads();

      float g = preval;
#pragma unroll
      for (int kk = 0; kk < 16; ++kk) g += redb[((kk << 4) + pos2) * 16 + v2];

      const float gA = __shfl_xor(g, 4);
      const float gB = __shfl_xor(g, 8);
      const float gC = __shfl_xor(g, 12);
      if (gate == 0) {
        const float iv = g, fv = gA, gv = gB, ov = gC;
        const float si = 1.0f / (1.0f + expf(-iv));
        const float sf = 1.0f / (1.0f + expf(-fv));
        const float so = 1.0f / (1.0f + expf(-ov));
        const float cn = sf * creg + si * tanhf(gv);
        const float hn = so * tanhf(cn);
        creg = cn;
        const int u = u0 + ul;
        hnxt[u * 32 + bb] = hn;
        if (ph == 1) dec_h[(t * 32 + bb) * 500 + u] = hn;
      }

      ++step;
      gbar3(flags, gen, step);
      float* tmpp = hcur; hcur = hnxt; hnxt = tmpp;
    }
  }
}

// ---------------- ablation kernels (diagnostic; outputs unconsumed) ----------
__global__ __launch_bounds__(256) void bar_only(unsigned* __restrict__ flags) {
  unsigned* gen = flags + 8192;
  for (unsigned s = 1; s <= 510; ++s) gbar3(flags, gen, s);
}

__global__ __launch_bounds__(256) void bar_hx(float* __restrict__ h_a,
                                              float* __restrict__ h_b,
                                              unsigned* __restrict__ flags) {
  __shared__ __align__(16) float hs[512 * 32];
  unsigned* gen = flags + 8192;
  const int tid = threadIdx.x;
  float* hcur = h_a;
  float* hnxt = h_b;
  for (unsigned s = 1; s <= 510; ++s) {
    for (int c = tid; c < 4000; c += 256)
      *(float4*)&hs[c * 4] = *(const float4*)&hcur[c * 4];
    __syncthreads();
    if (tid < 64)
      hnxt[((blockIdx.x * 2 + (tid >> 5)) << 5) + (tid & 31)] = hs[tid] * 0.999f;
    gbar3(flags, gen, s);
    float* t2 = hcur; hcur = hnxt; hnxt = t2;
  }
}

// ---------------- per-row log-softmax NLL ----------------
__device__ __forceinline__ float wave_max(float v) {
#pragma unroll
  for (int o = 32; o > 0; o >>= 1) v = fmaxf(v, __shfl_xor(v, o, 64));
  return v;
}
__device__ __forceinline__ float wave_sum(float v) {
#pragma unroll
  for (int o = 32; o > 0; o >>= 1) v += __shfl_xor(v, o, 64);
  return v;
}

__global__ __launch_bounds__(256) void loss_rows(
    const float* __restrict__ seq, const float* __restrict__ logits,
    const int* __restrict__ nseq, float* __restrict__ nll) {
  __shared__ float sm[8];
  const int r = blockIdx.x, tid = threadIdx.x;
  const int t = r >> 5, b = r & 31;
  const float* row = (t == 0) ? (seq + (long)b * VV)
                              : (logits + (long)((t - 1) * 32 + b) * VV);
  float m = -INFINITY;
  for (int c = tid; c < 1178; c += 256) {
    float4 v = *(const float4*)&row[c * 4];
    m = fmaxf(m, fmaxf(fmaxf(v.x, v.y), fmaxf(v.z, v.w)));
  }
  m = wave_max(m);
  const int wid = tid >> 6;
  if ((tid & 63) == 0) sm[wid] = m;
  __syncthreads();
  const float M4 = fmaxf(fmaxf(sm[0], sm[1]), fmaxf(sm[2], sm[3]));
  float s = 0.0f;
  for (int c = tid; c < 1178; c += 256) {
    float4 v = *(const float4*)&row[c * 4];
    s += expf(v.x - M4) + expf(v.y - M4) + expf(v.z - M4) + expf(v.w - M4);
  }
  s = wave_sum(s);
  if ((tid & 63) == 0) sm[4 + wid] = s;
  __syncthreads();
  if (tid == 0) {
    const float S = sm[4] + sm[5] + sm[6] + sm[7];
    const int tgt = nseq[(t << 5) + b];
    nll[r] = M4 + logf(S) - row[tgt];
  }
}

__global__ __launch_bounds__(256) void final_reduce(
    const float* __restrict__ nll, float* __restrict__ out) {
  __shared__ float sm[4];
  float s = 0.0f;
  for (int c = threadIdx.x; c < 8192; c += 256) s += nll[c];
  s = wave_sum(s);
  if ((threadIdx.x & 63) == 0) sm[threadIdx.x >> 6] = s;
  __syncthreads();
  if (threadIdx.x == 0) out[0] = (sm[0] + sm[1] + sm[2] + sm[3]) * (1.0f / 8192.0f);
}

// ---------------- launch ----------------
extern "C" void kernel_launch(void* const* d_in, const int* in_sizes, int n_in,
                              void* d_out, int out_size, void* d_ws, size_t ws_size,
                              hipStream_t stream) {
  (void)in_sizes; (void)n_in; (void)out_size; (void)ws_size;
  const float* seq  = (const float*)d_in[0];
  const int* nseq   = (const int*)d_in[1];
  const float* eWih = (const float*)d_in[2];
  const float* eWhh = (const float*)d_in[3];
  const float* ebih = (const float*)d_in[4];
  const float* ebhh = (const float*)d_in[5];
  const float* dWih = (const float*)d_in[6];
  const float* dWhh = (const float*)d_in[7];
  const float* dbih = (const float*)d_in[8];
  const float* dbhh = (const float*)d_in[9];
  const float* oW   = (const float*)d_in[10];
  const float* ob   = (const float*)d_in[11];

  float* wsf = (float*)d_ws;
  float* logits  = wsf;
  float* enc_pre = wsf;
  float* dec_pre = wsf + OFF_DECPRE;
  float* dec_h   = wsf + OFF_DECH;
  float* h_a     = wsf + OFF_HA;
  float* h_b     = wsf + OFF_HB;
  float* nll     = wsf + OFF_NLL;
  unsigned* flags = (unsigned*)(wsf + OFF_FLAGS);

  hipMemsetAsync(h_a, 0, 16000 * sizeof(float), stream);
  hipMemsetAsync(flags, 0, (8192 + 32) * sizeof(unsigned), stream);

  dim3 blk(256);
  gemm128<<<dim3(64, 16), blk, 0, stream>>>(seq, VV, 1, eWih, ebih, ebhh,
                                            enc_pre, FOURH, MPRE, FOURH, VV);
  gemm128<<<dim3(64, 16), blk, 0, stream>>>(seq, VV, 0, dWih, dbih, dbhh,
                                            dec_pre, FOURH, MPRE, FOURH, VV);
  lstm_rec<<<dim3(NBLK_REC), blk, 0, stream>>>(enc_pre, dec_pre, eWhh, dWhh,
                                               h_a, h_b, dec_h, flags);
  gemm128<<<dim3(64, 37), blk, 0, stream>>>(dec_h, HH, 0, oW, ob, nullptr,
                                            logits, VV, MPRE, VV, HH);
  loss_rows<<<dim3(8192), blk, 0, stream>>>(seq, logits, nseq, nll);
  final_reduce<<<dim3(1), blk, 0, stream>>>(nll, (float*)d_out);

  // ---- diagnostic ablations (logits region is dead now; re-zero their flags) ----
  unsigned* f1 = (unsigned*)(wsf + OFF_ABL1);
  unsigned* f2 = (unsigned*)(wsf + OFF_ABL2);
  hipMemsetAsync(f1, 0, 20000 * sizeof(float), stream);  // covers both regions
  bar_only<<<dim3(NBLK_REC), blk, 0, stream>>>(f1);
  bar_hx<<<dim3(NBLK_REC), blk, 0, stream>>>(h_a, h_b, f2);
}

// Round 4
// 14760.048 us; speedup vs baseline: 1.9151x; 1.9151x over previous
//
#include <hip/hip_runtime.h>
#include <math.h>

typedef unsigned long long ull;

// Problem constants
#define TT 256
#define BB 32
#define VV 4712
#define HH 500
#define FOURH 2000
#define MPRE 8160          // 255*32
#define NBLK_REC 250

// ---------------- workspace layout (float offsets) ----------------
// logits   : 0            .. 38,449,920   (8160*4712)
//   enc_preT: 0           .. 16,320,000   [2000][8160]   overlaps logits
//   dec_preT: 16,320,000  .. 32,640,000   [2000][8160]   overlaps logits
//   h_a     : 33,100,000  (16384 floats, [u][b] layout)  dead zone during rec
//   h_b     : 33,120,000  (16384 floats)
//   flags   : 33,140,000  (256 uints, packed)
// dec_h    : 38,449,920   .. 42,529,920   (8160*500)
// nll      : 42,561,920   .. 42,570,112   (8192)

#define OFF_DECPRE 16320000
#define OFF_HA     33100000
#define OFF_HB     33120000
#define OFF_FLAGS  33140000
#define OFF_DECH   38449920
#define OFF_NLL    42561920

// ---------------- fp32 tiled GEMM: C[m][n] = sum_k A[m][k]*W[row(n)][k] + bias
// bias_mode 0: + b0[n] (+ b1[n]); bias_mode 1: + b0[m] + b1[m]
// rowmapW 1: W row = reversed time mapping ((255-t)*32+b for n=t*32+b)
__global__ __launch_bounds__(256) void gemm128(
    const float* __restrict__ A, int lda,
    const float* __restrict__ W, int ldw, int rowmapW,
    int bias_mode, const float* __restrict__ b0, const float* __restrict__ b1,
    float* __restrict__ C, int ldc, int M, int N, int K) {
  __shared__ __align__(16) float As[16][132];
  __shared__ __align__(16) float Ws[16][132];
  const int tid = threadIdx.x;
  const int tx = tid & 15, ty = tid >> 4;
  const int m0 = blockIdx.x * 128, n0 = blockIdx.y * 128;

  float acc[2][2][4][4];
#pragma unroll
  for (int a = 0; a < 2; ++a)
#pragma unroll
    for (int b = 0; b < 2; ++b)
#pragma unroll
      for (int i = 0; i < 4; ++i)
#pragma unroll
        for (int j = 0; j < 4; ++j) acc[a][b][i][j] = 0.0f;

  const int srow = tid >> 2, kq0 = tid & 3;
  long arow[2];
  long wrow[2];
#pragma unroll
  for (int h = 0; h < 2; ++h) {
    int m = m0 + srow + h * 64;
    if (m >= M) m = M - 1;
    arow[h] = (long)m * lda;
    int n = n0 + srow + h * 64;
    if (n >= N) n = N - 1;
    int rn = n;
    if (rowmapW == 1) { int t = n >> 5, b = n & 31; rn = ((255 - t) << 5) + b; }
    wrow[h] = (long)rn * ldw;
  }

  const int KT = (K + 15) >> 4;
  for (int kt = 0; kt < KT; ++kt) {
    const int kbase = kt * 16 + kq0 * 4;
    const bool kok = (kbase < K);  // K multiple of 4 for all our calls
#pragma unroll
    for (int h = 0; h < 2; ++h) {
      float4 av = make_float4(0.f, 0.f, 0.f, 0.f);
      float4 wv = make_float4(0.f, 0.f, 0.f, 0.f);
      if (kok) {
        av = *(const float4*)&A[arow[h] + kbase];
        wv = *(const float4*)&W[wrow[h] + kbase];
      }
      const int ml = srow + h * 64;
      As[kq0 * 4 + 0][ml] = av.x; As[kq0 * 4 + 1][ml] = av.y;
      As[kq0 * 4 + 2][ml] = av.z; As[kq0 * 4 + 3][ml] = av.w;
      Ws[kq0 * 4 + 0][ml] = wv.x; Ws[kq0 * 4 + 1][ml] = wv.y;
      Ws[kq0 * 4 + 2][ml] = wv.z; Ws[kq0 * 4 + 3][ml] = wv.w;
    }
    __syncthreads();
#pragma unroll
    for (int k = 0; k < 16; ++k) {
      const float4 a0 = *(const float4*)&As[k][ty << 2];
      const float4 a1 = *(const float4*)&As[k][64 + (ty << 2)];
      const float4 w0 = *(const float4*)&Ws[k][tx << 2];
      const float4 w1 = *(const float4*)&Ws[k][64 + (tx << 2)];
      const float am[2][4] = {{a0.x, a0.y, a0.z, a0.w}, {a1.x, a1.y, a1.z, a1.w}};
      const float wn[2][4] = {{w0.x, w0.y, w0.z, w0.w}, {w1.x, w1.y, w1.z, w1.w}};
#pragma unroll
      for (int mh = 0; mh < 2; ++mh)
#pragma unroll
        for (int nh = 0; nh < 2; ++nh)
#pragma unroll
          for (int i = 0; i < 4; ++i)
#pragma unroll
            for (int j = 0; j < 4; ++j)
              acc[mh][nh][i][j] += am[mh][i] * wn[nh][j];
    }
    __syncthreads();
  }

  // epilogue
  float4 biascol[2];
#pragma unroll
  for (int nh = 0; nh < 2; ++nh) {
    biascol[nh] = make_float4(0.f, 0.f, 0.f, 0.f);
    const int n = n0 + nh * 64 + (tx << 2);
    if (bias_mode == 0 && n < N) {
      if (b0) {
        float4 v = *(const float4*)&b0[n];
        biascol[nh].x += v.x; biascol[nh].y += v.y; biascol[nh].z += v.z; biascol[nh].w += v.w;
      }
      if (b1) {
        float4 v = *(const float4*)&b1[n];
        biascol[nh].x += v.x; biascol[nh].y += v.y; biascol[nh].z += v.z; biascol[nh].w += v.w;
      }
    }
  }
#pragma unroll
  for (int mh = 0; mh < 2; ++mh)
#pragma unroll
    for (int i = 0; i < 4; ++i) {
      const int m = m0 + mh * 64 + (ty << 2) + i;
      if (m < M) {
        float rb = 0.0f;
        if (bias_mode == 1) rb = b0[m] + b1[m];
        float* crow = C + (long)m * ldc;
#pragma unroll
        for (int nh = 0; nh < 2; ++nh) {
          const int n = n0 + nh * 64 + (tx << 2);
          if (n < N) {
            float4 o;
            o.x = acc[mh][nh][i][0] + biascol[nh].x + rb;
            o.y = acc[mh][nh][i][1] + biascol[nh].y + rb;
            o.z = acc[mh][nh][i][2] + biascol[nh].z + rb;
            o.w = acc[mh][nh][i][3] + biascol[nh].w + rb;
            *(float4*)&crow[n] = o;
          }
        }
      }
    }
}

// ---------------- persistent LSTM recurrence, fence-free IC-atomic exchange ----
// 250 blocks x 2 units. h ping-pongs in global [u][b] layout; all cross-block
// traffic (h, flags) uses relaxed agent-scope atomics (served coherently at the
// Infinity Cache, no L2 invalidates, no wbl2 storms). Barrier = all-to-all:
// release-store own flag (after __syncthreads vmcnt-drain), every thread tid<250
// polls flags[tid] relaxed. No acquire fence needed: h loads are sc1 atomics.
__global__ __launch_bounds__(256) void lstm_rec(
    const float* __restrict__ enc_preT, const float* __restrict__ dec_preT,
    const float* __restrict__ enc_Whh, const float* __restrict__ dec_Whh,
    float* __restrict__ h_a, float* __restrict__ h_b,
    float* __restrict__ dec_h, unsigned* __restrict__ flags) {
  __shared__ __align__(16) float hs[512 * 32];   // [k][b] (64 KB)
  __shared__ __align__(16) float wsl[512 * 8];   // [k][r], zero-padded (16 KB)
  __shared__ __align__(16) float redb[16 * 16 * 16]; // k-split partials (16 KB)

  const int tid = threadIdx.x;
  const int ks = tid >> 4;          // 0..15 k-split
  const int tm = (tid & 15) >> 1;   // 0..7  b-group
  const int tn = tid & 1;           // 0..1  row-group
  const int u0 = blockIdx.x * 2;

  // reduce-stage mapping: this thread owns gate value (row, bb)
  const int v2 = tid & 15, pos2 = tid >> 4;
  const int row = ((pos2 & 1) << 2) + (v2 >> 2);   // 0..7
  const int bb  = ((pos2 >> 1) << 2) + (v2 & 3);   // 0..31
  const int gate = row & 3, ul = row >> 2;
  const long prebase = (long)(gate * 500 + u0 + ul) * MPRE + bb;  // + t*32

  float creg = 0.0f;   // cell state for (u0+ul, bb), valid on gate==0 threads

  const float* pres[2] = {enc_preT, dec_preT};
  const float* whhs[2] = {enc_Whh, dec_Whh};
  float* hcur = h_a;
  float* hnxt = h_b;
  unsigned step = 0;

  for (int ph = 0; ph < 2; ++ph) {
    const float* pre = pres[ph];
    const float* Whh = whhs[ph];
    __syncthreads();
    // stage Whh slice: local row r = ul*4+gate <- global row (r&3)*500 + u0 + (r>>2)
    for (int c = tid; c < 1024; c += 256) {
      const int r = c & 7, kq = c >> 3;
      const int k = kq << 2;
      float4 v = make_float4(0.f, 0.f, 0.f, 0.f);
      if (k < 500) {
        const int j = (r & 3) * 500 + u0 + (r >> 2);
        v = *(const float4*)&Whh[j * 500 + k];
      }
      wsl[(k + 0) * 8 + r] = v.x;
      wsl[(k + 1) * 8 + r] = v.y;
      wsl[(k + 2) * 8 + r] = v.z;
      wsl[(k + 3) * 8 + r] = v.w;
    }
    __syncthreads();

    for (int t = 0; t < 255; ++t) {
      // coalesced pre-activation read (preT layout: [gate*500+u][t*32+b])
      const float preval = pre[prebase + t * 32];

      // gather full h via relaxed IC atomics (8B each, 32/thread, pipelined)
      {
        const ull* src = (const ull*)hcur;
        ull* dst = (ull*)hs;
        for (int c = tid; c < 8192; c += 256) {
          dst[c] = __hip_atomic_load(&src[c], __ATOMIC_RELAXED,
                                     __HIP_MEMORY_SCOPE_AGENT);
        }
      }
      __syncthreads();

      float acc[4][4];
#pragma unroll
      for (int a = 0; a < 4; ++a)
#pragma unroll
        for (int b = 0; b < 4; ++b) acc[a][b] = 0.0f;

#pragma unroll
      for (int jj = 0; jj < 32; ++jj) {
        const int kl = (jj << 4) + ks;
        const float4 h4 = *(const float4*)&hs[kl * 32 + (tm << 2)];
        const float4 w4 = *(const float4*)&wsl[kl * 8 + (tn << 2)];
        acc[0][0] += w4.x * h4.x; acc[0][1] += w4.x * h4.y; acc[0][2] += w4.x * h4.z; acc[0][3] += w4.x * h4.w;
        acc[1][0] += w4.y * h4.x; acc[1][1] += w4.y * h4.y; acc[1][2] += w4.y * h4.z; acc[1][3] += w4.y * h4.w;
        acc[2][0] += w4.z * h4.x; acc[2][1] += w4.z * h4.y; acc[2][2] += w4.z * h4.z; acc[2][3] += w4.z * h4.w;
        acc[3][0] += w4.w * h4.x; acc[3][1] += w4.w * h4.y; acc[3][2] += w4.w * h4.z; acc[3][3] += w4.w * h4.w;
      }

      const int pos = (tm << 1) | tn;
#pragma unroll
      for (int r = 0; r < 4; ++r) {
        float4 v = make_float4(acc[r][0], acc[r][1], acc[r][2], acc[r][3]);
        *(float4*)&redb[((ks << 4) + pos) * 16 + (r << 2)] = v;
      }
      __syncthreads();

      float g = preval;
#pragma unroll
      for (int kk = 0; kk < 16; ++kk) g += redb[((kk << 4) + pos2) * 16 + v2];

      // gather 4 gates of (ul, bb) into gate==0 thread (rows differ in tid bits 2,3)
      const float gA = __shfl_xor(g, 4);
      const float gB = __shfl_xor(g, 8);
      const float gC = __shfl_xor(g, 12);
      if (gate == 0) {
        const float iv = g, fv = gA, gv = gB, ov = gC;
        const float si = 1.0f / (1.0f + expf(-iv));
        const float sf = 1.0f / (1.0f + expf(-fv));
        const float so = 1.0f / (1.0f + expf(-ov));
        const float cn = sf * creg + si * tanhf(gv);
        const float hn = so * tanhf(cn);
        creg = cn;
        const int u = u0 + ul;
        __hip_atomic_store(&hnxt[u * 32 + bb], hn, __ATOMIC_RELAXED,
                           __HIP_MEMORY_SCOPE_AGENT);
        if (ph == 1) dec_h[(t * 32 + bb) * 500 + u] = hn;
      }

      ++step;
      // all-to-all barrier: syncthreads drains each wave's vmcnt (h stores ACKed
      // at IC), then release-store own flag, poll everyone else's, resync.
      __syncthreads();
      if (tid == 0) {
        __hip_atomic_store(&flags[blockIdx.x], step, __ATOMIC_RELEASE,
                           __HIP_MEMORY_SCOPE_AGENT);
      }
      if (tid < NBLK_REC && tid != blockIdx.x) {
        while (__hip_atomic_load(&flags[tid], __ATOMIC_RELAXED,
                                 __HIP_MEMORY_SCOPE_AGENT) < step) {
          __builtin_amdgcn_s_sleep(1);
        }
      }
      __syncthreads();
      float* tmpp = hcur; hcur = hnxt; hnxt = tmpp;
    }
  }
}

// ---------------- per-row log-softmax NLL ----------------
__device__ __forceinline__ float wave_max(float v) {
#pragma unroll
  for (int o = 32; o > 0; o >>= 1) v = fmaxf(v, __shfl_xor(v, o, 64));
  return v;
}
__device__ __forceinline__ float wave_sum(float v) {
#pragma unroll
  for (int o = 32; o > 0; o >>= 1) v += __shfl_xor(v, o, 64);
  return v;
}

__global__ __launch_bounds__(256) void loss_rows(
    const float* __restrict__ seq, const float* __restrict__ logits,
    const int* __restrict__ nseq, float* __restrict__ nll) {
  __shared__ float sm[8];
  const int r = blockIdx.x, tid = threadIdx.x;
  const int t = r >> 5, b = r & 31;
  const float* row = (t == 0) ? (seq + (long)b * VV)
                              : (logits + (long)((t - 1) * 32 + b) * VV);
  float m = -INFINITY;
  for (int c = tid; c < 1178; c += 256) {  // 1178*4 = 4712 exactly
    float4 v = *(const float4*)&row[c * 4];
    m = fmaxf(m, fmaxf(fmaxf(v.x, v.y), fmaxf(v.z, v.w)));
  }
  m = wave_max(m);
  const int wid = tid >> 6;
  if ((tid & 63) == 0) sm[wid] = m;
  __syncthreads();
  const float M4 = fmaxf(fmaxf(sm[0], sm[1]), fmaxf(sm[2], sm[3]));
  float s = 0.0f;
  for (int c = tid; c < 1178; c += 256) {
    float4 v = *(const float4*)&row[c * 4];
    s += expf(v.x - M4) + expf(v.y - M4) + expf(v.z - M4) + expf(v.w - M4);
  }
  s = wave_sum(s);
  if ((tid & 63) == 0) sm[4 + wid] = s;
  __syncthreads();
  if (tid == 0) {
    const float S = sm[4] + sm[5] + sm[6] + sm[7];
    const int tgt = nseq[(t << 5) + b];
    nll[r] = M4 + logf(S) - row[tgt];
  }
}

__global__ __launch_bounds__(256) void final_reduce(
    const float* __restrict__ nll, float* __restrict__ out) {
  __shared__ float sm[4];
  float s = 0.0f;
  for (int c = threadIdx.x; c < 8192; c += 256) s += nll[c];
  s = wave_sum(s);
  if ((threadIdx.x & 63) == 0) sm[threadIdx.x >> 6] = s;
  __syncthreads();
  if (threadIdx.x == 0) out[0] = (sm[0] + sm[1] + sm[2] + sm[3]) * (1.0f / 8192.0f);
}

// ---------------- launch ----------------
extern "C" void kernel_launch(void* const* d_in, const int* in_sizes, int n_in,
                              void* d_out, int out_size, void* d_ws, size_t ws_size,
                              hipStream_t stream) {
  (void)in_sizes; (void)n_in; (void)out_size; (void)ws_size;
  const float* seq  = (const float*)d_in[0];
  const int* nseq   = (const int*)d_in[1];
  const float* eWih = (const float*)d_in[2];
  const float* eWhh = (const float*)d_in[3];
  const float* ebih = (const float*)d_in[4];
  const float* ebhh = (const float*)d_in[5];
  const float* dWih = (const float*)d_in[6];
  const float* dWhh = (const float*)d_in[7];
  const float* dbih = (const float*)d_in[8];
  const float* dbhh = (const float*)d_in[9];
  const float* oW   = (const float*)d_in[10];
  const float* ob   = (const float*)d_in[11];

  float* wsf = (float*)d_ws;
  float* logits   = wsf;
  float* enc_preT = wsf;
  float* dec_preT = wsf + OFF_DECPRE;
  float* h_a      = wsf + OFF_HA;
  float* h_b      = wsf + OFF_HB;
  float* dec_h    = wsf + OFF_DECH;
  float* nll      = wsf + OFF_NLL;
  unsigned* flags = (unsigned*)(wsf + OFF_FLAGS);

  hipMemsetAsync(h_a, 0, 16384 * sizeof(float), stream);
  hipMemsetAsync(h_b, 0, 16384 * sizeof(float), stream);
  hipMemsetAsync(flags, 0, 256 * sizeof(unsigned), stream);

  dim3 blk(256);
  // enc_preT[j][t*32+b] = eWih[j,:] . seq[(255-t)*32+b,:] + ebih[j]+ebhh[j]
  gemm128<<<dim3(16, 64), blk, 0, stream>>>(eWih, VV, seq, VV, 1,
                                            1, ebih, ebhh,
                                            enc_preT, MPRE, FOURH, MPRE, VV);
  // dec_preT[j][t*32+b] = dWih[j,:] . seq[t*32+b,:] + dbih[j]+dbhh[j]
  gemm128<<<dim3(16, 64), blk, 0, stream>>>(dWih, VV, seq, VV, 0,
                                            1, dbih, dbhh,
                                            dec_preT, MPRE, FOURH, MPRE, VV);
  // recurrence (encoder then decoder), writes dec_h
  lstm_rec<<<dim3(NBLK_REC), blk, 0, stream>>>(enc_preT, dec_preT, eWhh, dWhh,
                                               h_a, h_b, dec_h, flags);
  // logits = dec_h @ out_W^T + out_b  (overwrites preT buffers; dec_h disjoint)
  gemm128<<<dim3(64, 37), blk, 0, stream>>>(dec_h, HH, oW, HH, 0,
                                            0, ob, nullptr,
                                            logits, VV, MPRE, VV, HH);
  // per-row NLL then deterministic reduce
  loss_rows<<<dim3(8192), blk, 0, stream>>>(seq, logits, nseq, nll);
  final_reduce<<<dim3(1), blk, 0, stream>>>(nll, (float*)d_out);
}

// Round 5
// 9265.668 us; speedup vs baseline: 3.0508x; 1.5930x over previous
//
#include <hip/hip_runtime.h>
#include <math.h>

typedef unsigned long long ull;

// Problem constants
#define TT 256
#define BB 32
#define VV 4712
#define HH 500
#define FOURH 2000
#define MPRE 8160          // 255*32

// ---------------- workspace layout (float offsets) ----------------
// logits   : 0            .. 38,449,920   (8160*4712)
//   enc_preT: 0           .. 16,320,000   [2000][8160]   overlaps logits
//   dec_preT: 16,320,000  .. 32,640,000   [2000][8160]   overlaps logits
//   h_a     : 33,100,000  (16384 floats, [u][b] layout, u padded to 512)
//   h_b     : 33,120,000  (16384 floats)
//   flags   : 33,140,000  (512 uints: 8 groups x 64-slot stride)
// dec_h    : 38,449,920   .. 42,529,920   (8160*500)
// nll      : 42,561,920   .. 42,570,112   (8192)

#define OFF_DECPRE 16320000
#define OFF_HA     33100000
#define OFF_HB     33120000
#define OFF_FLAGS  33140000
#define OFF_DECH   38449920
#define OFF_NLL    42561920

// ---------------- fp32 tiled GEMM: C[m][n] = sum_k A[m][k]*W[row(n)][k] + bias
// bias_mode 0: + b0[n]; bias_mode 1: + b0[m] + b1[m]
// rowmapW 1: W row = reversed time mapping ((255-t)*32+b for n=t*32+b)
__global__ __launch_bounds__(256) void gemm128(
    const float* __restrict__ A, int lda,
    const float* __restrict__ W, int ldw, int rowmapW,
    int bias_mode, const float* __restrict__ b0, const float* __restrict__ b1,
    float* __restrict__ C, int ldc, int M, int N, int K) {
  __shared__ __align__(16) float As[16][132];
  __shared__ __align__(16) float Ws[16][132];
  const int tid = threadIdx.x;
  const int tx = tid & 15, ty = tid >> 4;
  const int m0 = blockIdx.x * 128, n0 = blockIdx.y * 128;

  float acc[2][2][4][4];
#pragma unroll
  for (int a = 0; a < 2; ++a)
#pragma unroll
    for (int b = 0; b < 2; ++b)
#pragma unroll
      for (int i = 0; i < 4; ++i)
#pragma unroll
        for (int j = 0; j < 4; ++j) acc[a][b][i][j] = 0.0f;

  const int srow = tid >> 2, kq0 = tid & 3;
  long arow[2];
  long wrow[2];
#pragma unroll
  for (int h = 0; h < 2; ++h) {
    int m = m0 + srow + h * 64;
    if (m >= M) m = M - 1;
    arow[h] = (long)m * lda;
    int n = n0 + srow + h * 64;
    if (n >= N) n = N - 1;
    int rn = n;
    if (rowmapW == 1) { int t = n >> 5, b = n & 31; rn = ((255 - t) << 5) + b; }
    wrow[h] = (long)rn * ldw;
  }

  const int KT = (K + 15) >> 4;
  for (int kt = 0; kt < KT; ++kt) {
    const int kbase = kt * 16 + kq0 * 4;
    const bool kok = (kbase < K);
#pragma unroll
    for (int h = 0; h < 2; ++h) {
      float4 av = make_float4(0.f, 0.f, 0.f, 0.f);
      float4 wv = make_float4(0.f, 0.f, 0.f, 0.f);
      if (kok) {
        av = *(const float4*)&A[arow[h] + kbase];
        wv = *(const float4*)&W[wrow[h] + kbase];
      }
      const int ml = srow + h * 64;
      As[kq0 * 4 + 0][ml] = av.x; As[kq0 * 4 + 1][ml] = av.y;
      As[kq0 * 4 + 2][ml] = av.z; As[kq0 * 4 + 3][ml] = av.w;
      Ws[kq0 * 4 + 0][ml] = wv.x; Ws[kq0 * 4 + 1][ml] = wv.y;
      Ws[kq0 * 4 + 2][ml] = wv.z; Ws[kq0 * 4 + 3][ml] = wv.w;
    }
    __syncthreads();
#pragma unroll
    for (int k = 0; k < 16; ++k) {
      const float4 a0 = *(const float4*)&As[k][ty << 2];
      const float4 a1 = *(const float4*)&As[k][64 + (ty << 2)];
      const float4 w0 = *(const float4*)&Ws[k][tx << 2];
      const float4 w1 = *(const float4*)&Ws[k][64 + (tx << 2)];
      const float am[2][4] = {{a0.x, a0.y, a0.z, a0.w}, {a1.x, a1.y, a1.z, a1.w}};
      const float wn[2][4] = {{w0.x, w0.y, w0.z, w0.w}, {w1.x, w1.y, w1.z, w1.w}};
#pragma unroll
      for (int mh = 0; mh < 2; ++mh)
#pragma unroll
        for (int nh = 0; nh < 2; ++nh)
#pragma unroll
          for (int i = 0; i < 4; ++i)
#pragma unroll
            for (int j = 0; j < 4; ++j)
              acc[mh][nh][i][j] += am[mh][i] * wn[nh][j];
    }
    __syncthreads();
  }

  float4 biascol[2];
#pragma unroll
  for (int nh = 0; nh < 2; ++nh) {
    biascol[nh] = make_float4(0.f, 0.f, 0.f, 0.f);
    const int n = n0 + nh * 64 + (tx << 2);
    if (bias_mode == 0 && n < N) {
      if (b0) {
        float4 v = *(const float4*)&b0[n];
        biascol[nh].x += v.x; biascol[nh].y += v.y; biascol[nh].z += v.z; biascol[nh].w += v.w;
      }
      if (b1) {
        float4 v = *(const float4*)&b1[n];
        biascol[nh].x += v.x; biascol[nh].y += v.y; biascol[nh].z += v.z; biascol[nh].w += v.w;
      }
    }
  }
#pragma unroll
  for (int mh = 0; mh < 2; ++mh)
#pragma unroll
    for (int i = 0; i < 4; ++i) {
      const int m = m0 + mh * 64 + (ty << 2) + i;
      if (m < M) {
        float rb = 0.0f;
        if (bias_mode == 1) rb = b0[m] + b1[m];
        float* crow = C + (long)m * ldc;
#pragma unroll
        for (int nh = 0; nh < 2; ++nh) {
          const int n = n0 + nh * 64 + (tx << 2);
          if (n < N) {
            float4 o;
            o.x = acc[mh][nh][i][0] + biascol[nh].x + rb;
            o.y = acc[mh][nh][i][1] + biascol[nh].y + rb;
            o.z = acc[mh][nh][i][2] + biascol[nh].z + rb;
            o.w = acc[mh][nh][i][3] + biascol[nh].w + rb;
            *(float4*)&crow[n] = o;
          }
        }
      }
    }
}

// ---------------- persistent LSTM recurrence, 2D-partitioned -------------------
// Grid 256 = 32 unit-tiles (X: 16 units each, last tile padded) x 8 batch groups
// (Y: 4 cols each). Batch groups are fully independent (separate h columns,
// separate flags) -> 8 free-running 32-block barrier groups.
// Per block: Whh slice (64 gate-rows x 500) LDS-resident; per step gather only
// h[:, b0..b0+3] (8 KB, 1000 x 8B relaxed IC atomics); 256 threads = (ul,g,c),
// each computes one full 500-dot; gates combined via in-wave shfl_xor.
// All global stores are relaxed agent atomics (IC-point, no dirty L2).
__global__ __launch_bounds__(256, 1) void lstm_rec(
    const float* __restrict__ enc_preT, const float* __restrict__ dec_preT,
    const float* __restrict__ enc_Whh, const float* __restrict__ dec_Whh,
    float* __restrict__ h_a, float* __restrict__ h_b,
    float* __restrict__ dec_h, unsigned* __restrict__ flags) {
  __shared__ __align__(16) float wsl[64 * 516];  // [r][k], pitch 516 (129 f4), 132 KB
  __shared__ __align__(16) float hs[4 * 516];    // [c][k], pitch 516, 8.25 KB

  const int tid = threadIdx.x;
  const int X = blockIdx.x & 31, Y = blockIdx.x >> 5;
  const int u0 = X * 16, b0 = Y * 4;
  unsigned* gflags = flags + Y * 64;

  const int c  = tid & 3;
  const int g  = (tid >> 2) & 3;
  const int ul = tid >> 4;
  const int r  = ul * 4 + g;            // local gate-row 0..63
  const int u  = u0 + ul;               // global unit (may be >=500 on X=31 pad)
  const int usafe = (u < 500) ? u : 499;
  const long prerow = (long)(g * 500 + usafe) * MPRE + b0 + c;   // + t*32

  // zero k-pads (500..515) of hs once
  if (tid < 16)
    ((float4*)hs)[(tid >> 2) * 129 + 125 + (tid & 3)] =
        make_float4(0.f, 0.f, 0.f, 0.f);

  float creg = 0.0f;   // cell state for (u, b0+c), live on g==0 threads

  const float* pres[2] = {enc_preT, dec_preT};
  const float* whhs[2] = {enc_Whh, dec_Whh};
  float* hcur = h_a;
  float* hnxt = h_b;
  unsigned step = 0;

  for (int ph = 0; ph < 2; ++ph) {
    const float* pre = pres[ph];
    const float* Whh = whhs[ph];
    __syncthreads();   // wsl readers of previous phase done
    // stage Whh slice: wsl[rr][k] <- Whh[(rr&3)*500 + u0 + (rr>>2)][k]
    for (int idx = tid; idx < 8000; idx += 256) {
      const int rr = idx / 125, i = idx - rr * 125;
      const int uu = u0 + (rr >> 2);
      float4 v = make_float4(0.f, 0.f, 0.f, 0.f);
      if (uu < 500)
        v = *(const float4*)&Whh[(long)((rr & 3) * 500 + uu) * 500 + i * 4];
      ((float4*)wsl)[rr * 129 + i] = v;
    }
    // zero w k-pads: rr = tid>>2, f4 slot 125+(tid&3)
    ((float4*)wsl)[(tid >> 2) * 129 + 125 + (tid & 3)] =
        make_float4(0.f, 0.f, 0.f, 0.f);
    __syncthreads();

    for (int t = 0; t < 255; ++t) {
      // prefetch pre-activation (L2-warm plain load, independent of h)
      const float preval = pre[prerow + t * 32];

      // gather h[:, b0..b0+3]: 1000 x 8B relaxed IC atomics, transpose into hs
      {
        const ull* src = (const ull*)hcur;
        for (int idx = tid; idx < 1000; idx += 256) {
          const int uu = idx >> 1, e = idx & 1;
          const ull v = __hip_atomic_load(&src[uu * 16 + (b0 >> 1) + e],
                                          __ATOMIC_RELAXED,
                                          __HIP_MEMORY_SCOPE_AGENT);
          union { ull q; float f[2]; } cv; cv.q = v;
          hs[(2 * e + 0) * 516 + uu] = cv.f[0];
          hs[(2 * e + 1) * 516 + uu] = cv.f[1];
        }
      }
      __syncthreads();

      // full-length dot: 129 f4 iters (pads are zero), 4 independent chains
      const float4* w4 = (const float4*)wsl + r * 129;
      const float4* h4 = (const float4*)hs + c * 129;
      float ax = 0.f, ay = 0.f, az = 0.f, aw = 0.f;
#pragma unroll 8
      for (int i = 0; i < 129; ++i) {
        const float4 w = w4[i];
        const float4 h = h4[i];
        ax += w.x * h.x; ay += w.y * h.y; az += w.z * h.z; aw += w.w * h.w;
      }
      const float gv = (ax + ay) + (az + aw) + preval;

      // combine 4 gates of (ul, c) on the g==0 lane (g lives in tid bits 2-3)
      const float gA = __shfl_xor(gv, 4);
      const float gB = __shfl_xor(gv, 8);
      const float gC = __shfl_xor(gv, 12);
      if (g == 0) {
        const float iv = gv, fv = gA, ggv = gB, ov = gC;
        const float si = 1.0f / (1.0f + expf(-iv));
        const float sf = 1.0f / (1.0f + expf(-fv));
        const float so = 1.0f / (1.0f + expf(-ov));
        const float cn = sf * creg + si * tanhf(ggv);
        const float hn = so * tanhf(cn);
        creg = cn;
        __hip_atomic_store(&hnxt[u * 32 + b0 + c], hn, __ATOMIC_RELAXED,
                           __HIP_MEMORY_SCOPE_AGENT);   // u>=500 lands in pad
        if (ph == 1 && u < 500)
          __hip_atomic_store(&dec_h[(long)(t * 32 + b0 + c) * 500 + u], hn,
                             __ATOMIC_RELAXED, __HIP_MEMORY_SCOPE_AGENT);
      }

      ++step;
      // group barrier: syncthreads drains vmcnt (h stores ACKed at IC),
      // release-publish own flag, poll the 31 peers, resync.
      __syncthreads();
      if (tid == 0)
        __hip_atomic_store(&gflags[X], step, __ATOMIC_RELEASE,
                           __HIP_MEMORY_SCOPE_AGENT);
      if (tid < 32 && tid != X) {
        while (__hip_atomic_load(&gflags[tid], __ATOMIC_RELAXED,
                                 __HIP_MEMORY_SCOPE_AGENT) < step) {
          __builtin_amdgcn_s_sleep(1);
        }
      }
      __syncthreads();
      float* tmpp = hcur; hcur = hnxt; hnxt = tmpp;
    }
  }
}

// ---------------- per-row log-softmax NLL ----------------
__device__ __forceinline__ float wave_max(float v) {
#pragma unroll
  for (int o = 32; o > 0; o >>= 1) v = fmaxf(v, __shfl_xor(v, o, 64));
  return v;
}
__device__ __forceinline__ float wave_sum(float v) {
#pragma unroll
  for (int o = 32; o > 0; o >>= 1) v += __shfl_xor(v, o, 64);
  return v;
}

__global__ __launch_bounds__(256) void loss_rows(
    const float* __restrict__ seq, const float* __restrict__ logits,
    const int* __restrict__ nseq, float* __restrict__ nll) {
  __shared__ float sm[8];
  const int r = blockIdx.x, tid = threadIdx.x;
  const int t = r >> 5, b = r & 31;
  const float* row = (t == 0) ? (seq + (long)b * VV)
                              : (logits + (long)((t - 1) * 32 + b) * VV);
  float m = -INFINITY;
  for (int c = tid; c < 1178; c += 256) {  // 1178*4 = 4712 exactly
    float4 v = *(const float4*)&row[c * 4];
    m = fmaxf(m, fmaxf(fmaxf(v.x, v.y), fmaxf(v.z, v.w)));
  }
  m = wave_max(m);
  const int wid = tid >> 6;
  if ((tid & 63) == 0) sm[wid] = m;
  __syncthreads();
  const float M4 = fmaxf(fmaxf(sm[0], sm[1]), fmaxf(sm[2], sm[3]));
  float s = 0.0f;
  for (int c = tid; c < 1178; c += 256) {
    float4 v = *(const float4*)&row[c * 4];
    s += expf(v.x - M4) + expf(v.y - M4) + expf(v.z - M4) + expf(v.w - M4);
  }
  s = wave_sum(s);
  if ((tid & 63) == 0) sm[4 + wid] = s;
  __syncthreads();
  if (tid == 0) {
    const float S = sm[4] + sm[5] + sm[6] + sm[7];
    const int tgt = nseq[(t << 5) + b];
    nll[r] = M4 + logf(S) - row[tgt];
  }
}

__global__ __launch_bounds__(256) void final_reduce(
    const float* __restrict__ nll, float* __restrict__ out) {
  __shared__ float sm[4];
  float s = 0.0f;
  for (int c = threadIdx.x; c < 8192; c += 256) s += nll[c];
  s = wave_sum(s);
  if ((threadIdx.x & 63) == 0) sm[threadIdx.x >> 6] = s;
  __syncthreads();
  if (threadIdx.x == 0) out[0] = (sm[0] + sm[1] + sm[2] + sm[3]) * (1.0f / 8192.0f);
}

// ---------------- launch ----------------
extern "C" void kernel_launch(void* const* d_in, const int* in_sizes, int n_in,
                              void* d_out, int out_size, void* d_ws, size_t ws_size,
                              hipStream_t stream) {
  (void)in_sizes; (void)n_in; (void)out_size; (void)ws_size;
  const float* seq  = (const float*)d_in[0];
  const int* nseq   = (const int*)d_in[1];
  const float* eWih = (const float*)d_in[2];
  const float* eWhh = (const float*)d_in[3];
  const float* ebih = (const float*)d_in[4];
  const float* ebhh = (const float*)d_in[5];
  const float* dWih = (const float*)d_in[6];
  const float* dWhh = (const float*)d_in[7];
  const float* dbih = (const float*)d_in[8];
  const float* dbhh = (const float*)d_in[9];
  const float* oW   = (const float*)d_in[10];
  const float* ob   = (const float*)d_in[11];

  float* wsf = (float*)d_ws;
  float* logits   = wsf;
  float* enc_preT = wsf;
  float* dec_preT = wsf + OFF_DECPRE;
  float* h_a      = wsf + OFF_HA;
  float* h_b      = wsf + OFF_HB;
  float* dec_h    = wsf + OFF_DECH;
  float* nll      = wsf + OFF_NLL;
  unsigned* flags = (unsigned*)(wsf + OFF_FLAGS);

  hipMemsetAsync(h_a, 0, 16384 * sizeof(float), stream);
  hipMemsetAsync(h_b, 0, 16384 * sizeof(float), stream);
  hipMemsetAsync(flags, 0, 512 * sizeof(unsigned), stream);

  dim3 blk(256);
  // enc_preT[j][t*32+b] = eWih[j,:] . seq[(255-t)*32+b,:] + ebih[j]+ebhh[j]
  gemm128<<<dim3(16, 64), blk, 0, stream>>>(eWih, VV, seq, VV, 1,
                                            1, ebih, ebhh,
                                            enc_preT, MPRE, FOURH, MPRE, VV);
  // dec_preT[j][t*32+b] = dWih[j,:] . seq[t*32+b,:] + dbih[j]+dbhh[j]
  gemm128<<<dim3(16, 64), blk, 0, stream>>>(dWih, VV, seq, VV, 0,
                                            1, dbih, dbhh,
                                            dec_preT, MPRE, FOURH, MPRE, VV);
  // recurrence (encoder then decoder), writes dec_h
  lstm_rec<<<dim3(256), blk, 0, stream>>>(enc_preT, dec_preT, eWhh, dWhh,
                                          h_a, h_b, dec_h, flags);
  // logits = dec_h @ out_W^T + out_b  (overwrites preT buffers; dec_h disjoint)
  gemm128<<<dim3(64, 37), blk, 0, stream>>>(dec_h, HH, oW, HH, 0,
                                            0, ob, nullptr,
                                            logits, VV, MPRE, VV, HH);
  // per-row NLL then deterministic reduce
  loss_rows<<<dim3(8192), blk, 0, stream>>>(seq, logits, nseq, nll);
  final_reduce<<<dim3(1), blk, 0, stream>>>(nll, (float*)d_out);
}

// Round 6
// 6852.733 us; speedup vs baseline: 4.1250x; 1.3521x over previous
//
#include <hip/hip_runtime.h>
#include <math.h>

typedef unsigned long long ull;
typedef __attribute__((ext_vector_type(8))) short s16x8;
typedef __attribute__((ext_vector_type(8))) unsigned short u16x8;
typedef __attribute__((ext_vector_type(4))) float f32x4;

// Problem constants
#define TT 256
#define BB 32
#define VV 4712
#define HH 500
#define FOURH 2000
#define MPRE 8160          // 255*32

// ---------------- workspace layout (float offsets) ----------------
#define OFF_DECPRE 16320000
#define OFF_HA     33100000
#define OFF_HB     33120000
#define OFF_FLAGS  33140000
#define OFF_DECH   38449920
#define OFF_NLL    42561920

__device__ __forceinline__ unsigned short f2b(float f) {
  unsigned int b = __float_as_uint(f);
  b = b + 0x7fffu + ((b >> 16) & 1u);   // round-to-nearest-even bf16
  return (unsigned short)(b >> 16);
}

// ---------------- bf16 MFMA GEMM: C[m][n] = sum_k A[m][k]*W[row(n)][k] + bias
// 128x128 tile, 4 waves (2x2), each wave 64x64 = 4x4 frags of 16x16x32 MFMA.
// fp32 inputs converted to bf16 during LDS staging (RNE). LDS rows padded to
// 40 ushorts (80B -> 2-way bank alias on frag reads = free).
// bias_mode 0: + b0[n]; bias_mode 1: + b0[m] + b1[m]
// rowmapW 1: W row = reversed time mapping ((255-t)*32+b for n=t*32+b)
__global__ __launch_bounds__(256) void gemm_bf16(
    const float* __restrict__ A, int lda,
    const float* __restrict__ W, int ldw, int rowmapW,
    int bias_mode, const float* __restrict__ b0, const float* __restrict__ b1,
    float* __restrict__ C, int ldc, int M, int N, int K) {
  __shared__ __align__(16) unsigned short As[128 * 40];
  __shared__ __align__(16) unsigned short Bs[128 * 40];

  const int tid = threadIdx.x;
  const int lane = tid & 63, wid = tid >> 6;
  const int wm = wid >> 1, wn = wid & 1;        // 2x2 wave grid
  const int row16 = lane & 15, kq = lane >> 4;  // frag row/col + k-group
  const int m0 = blockIdx.x * 128, n0 = blockIdx.y * 128;

  // staging mapping: thread -> (row 0..127, k-half 0/16)
  const int sr = tid >> 1;
  const int ks = (tid & 1) << 4;
  int am = m0 + sr; if (am >= M) am = M - 1;
  const float* arow = A + (long)am * lda;
  int nn = n0 + sr; if (nn >= N) nn = N - 1;
  int rn = nn;
  if (rowmapW) { int t = nn >> 5, b = nn & 31; rn = ((255 - t) << 5) + b; }
  const float* wrow = W + (long)rn * ldw;

  f32x4 acc[4][4];
#pragma unroll
  for (int i = 0; i < 4; ++i)
#pragma unroll
    for (int j = 0; j < 4; ++j) acc[i][j] = (f32x4){0.f, 0.f, 0.f, 0.f};

  const int KT = (K + 31) >> 5;
  for (int kt = 0; kt < KT; ++kt) {
    const int kb = kt * 32 + ks;
    float4 av[4], wv[4];
#pragma unroll
    for (int q = 0; q < 4; ++q) {
      const int k = kb + q * 4;     // K is a multiple of 4 in all our calls
      if (k < K) {
        av[q] = *(const float4*)(arow + k);
        wv[q] = *(const float4*)(wrow + k);
      } else {
        av[q] = make_float4(0.f, 0.f, 0.f, 0.f);
        wv[q] = make_float4(0.f, 0.f, 0.f, 0.f);
      }
    }
    const u16x8 pa0 = {f2b(av[0].x), f2b(av[0].y), f2b(av[0].z), f2b(av[0].w),
                       f2b(av[1].x), f2b(av[1].y), f2b(av[1].z), f2b(av[1].w)};
    const u16x8 pa1 = {f2b(av[2].x), f2b(av[2].y), f2b(av[2].z), f2b(av[2].w),
                       f2b(av[3].x), f2b(av[3].y), f2b(av[3].z), f2b(av[3].w)};
    const u16x8 pw0 = {f2b(wv[0].x), f2b(wv[0].y), f2b(wv[0].z), f2b(wv[0].w),
                       f2b(wv[1].x), f2b(wv[1].y), f2b(wv[1].z), f2b(wv[1].w)};
    const u16x8 pw1 = {f2b(wv[2].x), f2b(wv[2].y), f2b(wv[2].z), f2b(wv[2].w),
                       f2b(wv[3].x), f2b(wv[3].y), f2b(wv[3].z), f2b(wv[3].w)};

    __syncthreads();   // previous iteration's frag readers done
    *(u16x8*)&As[sr * 40 + ks + 0] = pa0;
    *(u16x8*)&As[sr * 40 + ks + 8] = pa1;
    *(u16x8*)&Bs[sr * 40 + ks + 0] = pw0;
    *(u16x8*)&Bs[sr * 40 + ks + 8] = pw1;
    __syncthreads();

    s16x8 afrag[4], bfrag[4];
#pragma unroll
    for (int i = 0; i < 4; ++i)
      afrag[i] = *(const s16x8*)&As[(wm * 64 + i * 16 + row16) * 40 + kq * 8];
#pragma unroll
    for (int j = 0; j < 4; ++j)
      bfrag[j] = *(const s16x8*)&Bs[(wn * 64 + j * 16 + row16) * 40 + kq * 8];
#pragma unroll
    for (int i = 0; i < 4; ++i)
#pragma unroll
      for (int j = 0; j < 4; ++j)
        acc[i][j] = __builtin_amdgcn_mfma_f32_16x16x32_bf16(
            afrag[i], bfrag[j], acc[i][j], 0, 0, 0);
  }

  // epilogue: C/D layout col = lane&15, row = (lane>>4)*4 + reg  [m89/m91]
#pragma unroll
  for (int i = 0; i < 4; ++i) {
    const int rbase = m0 + wm * 64 + i * 16 + kq * 4;
#pragma unroll
    for (int r = 0; r < 4; ++r) {
      const int mrow = rbase + r;
      if (mrow < M) {
        const float rb = (bias_mode == 1) ? (b0[mrow] + b1[mrow]) : 0.0f;
        float* crow = C + (long)mrow * ldc;
#pragma unroll
        for (int j = 0; j < 4; ++j) {
          const int col = n0 + wn * 64 + j * 16 + row16;
          if (col < N) {
            float v = acc[i][j][r] + rb;
            if (bias_mode == 0 && b0) v += b0[col];
            crow[col] = v;
          }
        }
      }
    }
  }
}

// ---------------- persistent LSTM recurrence, 2D-partitioned (unchanged r5) ---
__global__ __launch_bounds__(256, 1) void lstm_rec(
    const float* __restrict__ enc_preT, const float* __restrict__ dec_preT,
    const float* __restrict__ enc_Whh, const float* __restrict__ dec_Whh,
    float* __restrict__ h_a, float* __restrict__ h_b,
    float* __restrict__ dec_h, unsigned* __restrict__ flags) {
  __shared__ __align__(16) float wsl[64 * 516];  // [r][k], pitch 516 (129 f4)
  __shared__ __align__(16) float hs[4 * 516];    // [c][k], pitch 516

  const int tid = threadIdx.x;
  const int X = blockIdx.x & 31, Y = blockIdx.x >> 5;
  const int u0 = X * 16, b0 = Y * 4;
  unsigned* gflags = flags + Y * 64;

  const int c  = tid & 3;
  const int g  = (tid >> 2) & 3;
  const int ul = tid >> 4;
  const int r  = ul * 4 + g;
  const int u  = u0 + ul;
  const int usafe = (u < 500) ? u : 499;
  const long prerow = (long)(g * 500 + usafe) * MPRE + b0 + c;

  if (tid < 16)
    ((float4*)hs)[(tid >> 2) * 129 + 125 + (tid & 3)] =
        make_float4(0.f, 0.f, 0.f, 0.f);

  float creg = 0.0f;

  const float* pres[2] = {enc_preT, dec_preT};
  const float* whhs[2] = {enc_Whh, dec_Whh};
  float* hcur = h_a;
  float* hnxt = h_b;
  unsigned step = 0;

  for (int ph = 0; ph < 2; ++ph) {
    const float* pre = pres[ph];
    const float* Whh = whhs[ph];
    __syncthreads();
    for (int idx = tid; idx < 8000; idx += 256) {
      const int rr = idx / 125, i = idx - rr * 125;
      const int uu = u0 + (rr >> 2);
      float4 v = make_float4(0.f, 0.f, 0.f, 0.f);
      if (uu < 500)
        v = *(const float4*)&Whh[(long)((rr & 3) * 500 + uu) * 500 + i * 4];
      ((float4*)wsl)[rr * 129 + i] = v;
    }
    ((float4*)wsl)[(tid >> 2) * 129 + 125 + (tid & 3)] =
        make_float4(0.f, 0.f, 0.f, 0.f);
    __syncthreads();

    for (int t = 0; t < 255; ++t) {
      const float preval = pre[prerow + t * 32];

      {
        const ull* src = (const ull*)hcur;
        for (int idx = tid; idx < 1000; idx += 256) {
          const int uu = idx >> 1, e = idx & 1;
          const ull v = __hip_atomic_load(&src[uu * 16 + (b0 >> 1) + e],
                                          __ATOMIC_RELAXED,
                                          __HIP_MEMORY_SCOPE_AGENT);
          union { ull q; float f[2]; } cv; cv.q = v;
          hs[(2 * e + 0) * 516 + uu] = cv.f[0];
          hs[(2 * e + 1) * 516 + uu] = cv.f[1];
        }
      }
      __syncthreads();

      const float4* w4 = (const float4*)wsl + r * 129;
      const float4* h4 = (const float4*)hs + c * 129;
      float ax = 0.f, ay = 0.f, az = 0.f, aw = 0.f;
#pragma unroll 8
      for (int i = 0; i < 129; ++i) {
        const float4 w = w4[i];
        const float4 h = h4[i];
        ax += w.x * h.x; ay += w.y * h.y; az += w.z * h.z; aw += w.w * h.w;
      }
      const float gv = (ax + ay) + (az + aw) + preval;

      const float gA = __shfl_xor(gv, 4);
      const float gB = __shfl_xor(gv, 8);
      const float gC = __shfl_xor(gv, 12);
      if (g == 0) {
        const float iv = gv, fv = gA, ggv = gB, ov = gC;
        const float si = 1.0f / (1.0f + expf(-iv));
        const float sf = 1.0f / (1.0f + expf(-fv));
        const float so = 1.0f / (1.0f + expf(-ov));
        const float cn = sf * creg + si * tanhf(ggv);
        const float hn = so * tanhf(cn);
        creg = cn;
        __hip_atomic_store(&hnxt[u * 32 + b0 + c], hn, __ATOMIC_RELAXED,
                           __HIP_MEMORY_SCOPE_AGENT);
        if (ph == 1 && u < 500)
          __hip_atomic_store(&dec_h[(long)(t * 32 + b0 + c) * 500 + u], hn,
                             __ATOMIC_RELAXED, __HIP_MEMORY_SCOPE_AGENT);
      }

      ++step;
      __syncthreads();
      if (tid == 0)
        __hip_atomic_store(&gflags[X], step, __ATOMIC_RELEASE,
                           __HIP_MEMORY_SCOPE_AGENT);
      if (tid < 32 && tid != X) {
        while (__hip_atomic_load(&gflags[tid], __ATOMIC_RELAXED,
                                 __HIP_MEMORY_SCOPE_AGENT) < step) {
          __builtin_amdgcn_s_sleep(1);
        }
      }
      __syncthreads();
      float* tmpp = hcur; hcur = hnxt; hnxt = tmpp;
    }
  }
}

// ---------------- per-row log-softmax NLL ----------------
__device__ __forceinline__ float wave_max(float v) {
#pragma unroll
  for (int o = 32; o > 0; o >>= 1) v = fmaxf(v, __shfl_xor(v, o, 64));
  return v;
}
__device__ __forceinline__ float wave_sum(float v) {
#pragma unroll
  for (int o = 32; o > 0; o >>= 1) v += __shfl_xor(v, o, 64);
  return v;
}

__global__ __launch_bounds__(256) void loss_rows(
    const float* __restrict__ seq, const float* __restrict__ logits,
    const int* __restrict__ nseq, float* __restrict__ nll) {
  __shared__ float sm[8];
  const int r = blockIdx.x, tid = threadIdx.x;
  const int t = r >> 5, b = r & 31;
  const float* row = (t == 0) ? (seq + (long)b * VV)
                              : (logits + (long)((t - 1) * 32 + b) * VV);
  float m = -INFINITY;
  for (int c = tid; c < 1178; c += 256) {
    float4 v = *(const float4*)&row[c * 4];
    m = fmaxf(m, fmaxf(fmaxf(v.x, v.y), fmaxf(v.z, v.w)));
  }
  m = wave_max(m);
  const int wid = tid >> 6;
  if ((tid & 63) == 0) sm[wid] = m;
  __syncthreads();
  const float M4 = fmaxf(fmaxf(sm[0], sm[1]), fmaxf(sm[2], sm[3]));
  float s = 0.0f;
  for (int c = tid; c < 1178; c += 256) {
    float4 v = *(const float4*)&row[c * 4];
    s += expf(v.x - M4) + expf(v.y - M4) + expf(v.z - M4) + expf(v.w - M4);
  }
  s = wave_sum(s);
  if ((tid & 63) == 0) sm[4 + wid] = s;
  __syncthreads();
  if (tid == 0) {
    const float S = sm[4] + sm[5] + sm[6] + sm[7];
    const int tgt = nseq[(t << 5) + b];
    nll[r] = M4 + logf(S) - row[tgt];
  }
}

__global__ __launch_bounds__(256) void final_reduce(
    const float* __restrict__ nll, float* __restrict__ out) {
  __shared__ float sm[4];
  float s = 0.0f;
  for (int c = threadIdx.x; c < 8192; c += 256) s += nll[c];
  s = wave_sum(s);
  if ((threadIdx.x & 63) == 0) sm[threadIdx.x >> 6] = s;
  __syncthreads();
  if (threadIdx.x == 0) out[0] = (sm[0] + sm[1] + sm[2] + sm[3]) * (1.0f / 8192.0f);
}

// ---------------- launch ----------------
extern "C" void kernel_launch(void* const* d_in, const int* in_sizes, int n_in,
                              void* d_out, int out_size, void* d_ws, size_t ws_size,
                              hipStream_t stream) {
  (void)in_sizes; (void)n_in; (void)out_size; (void)ws_size;
  const float* seq  = (const float*)d_in[0];
  const int* nseq   = (const int*)d_in[1];
  const float* eWih = (const float*)d_in[2];
  const float* eWhh = (const float*)d_in[3];
  const float* ebih = (const float*)d_in[4];
  const float* ebhh = (const float*)d_in[5];
  const float* dWih = (const float*)d_in[6];
  const float* dWhh = (const float*)d_in[7];
  const float* dbih = (const float*)d_in[8];
  const float* dbhh = (const float*)d_in[9];
  const float* oW   = (const float*)d_in[10];
  const float* ob   = (const float*)d_in[11];

  float* wsf = (float*)d_ws;
  float* logits   = wsf;
  float* enc_preT = wsf;
  float* dec_preT = wsf + OFF_DECPRE;
  float* h_a      = wsf + OFF_HA;
  float* h_b      = wsf + OFF_HB;
  float* dec_h    = wsf + OFF_DECH;
  float* nll      = wsf + OFF_NLL;
  unsigned* flags = (unsigned*)(wsf + OFF_FLAGS);

  hipMemsetAsync(h_a, 0, 16384 * sizeof(float), stream);
  hipMemsetAsync(h_b, 0, 16384 * sizeof(float), stream);
  hipMemsetAsync(flags, 0, 512 * sizeof(unsigned), stream);

  dim3 blk(256);
  // enc_preT[j][t*32+b] = eWih[j,:] . seq[(255-t)*32+b,:] + ebih[j]+ebhh[j]
  gemm_bf16<<<dim3(16, 64), blk, 0, stream>>>(eWih, VV, seq, VV, 1,
                                              1, ebih, ebhh,
                                              enc_preT, MPRE, FOURH, MPRE, VV);
  // dec_preT[j][t*32+b] = dWih[j,:] . seq[t*32+b,:] + dbih[j]+dbhh[j]
  gemm_bf16<<<dim3(16, 64), blk, 0, stream>>>(dWih, VV, seq, VV, 0,
                                              1, dbih, dbhh,
                                              dec_preT, MPRE, FOURH, MPRE, VV);
  // recurrence (encoder then decoder), writes dec_h
  lstm_rec<<<dim3(256), blk, 0, stream>>>(enc_preT, dec_preT, eWhh, dWhh,
                                          h_a, h_b, dec_h, flags);
  // logits = dec_h @ out_W^T + out_b  (overwrites preT buffers; dec_h disjoint)
  gemm_bf16<<<dim3(64, 37), blk, 0, stream>>>(dec_h, HH, oW, HH, 0,
                                              0, ob, nullptr,
                                              logits, VV, MPRE, VV, HH);
  // per-row NLL then deterministic reduce
  loss_rows<<<dim3(8192), blk, 0, stream>>>(seq, logits, nseq, nll);
  final_reduce<<<dim3(1), blk, 0, stream>>>(nll, (float*)d_out);
}

// Round 7
// 5039.508 us; speedup vs baseline: 5.6092x; 1.3598x over previous
//
#include <hip/hip_runtime.h>
#include <math.h>

typedef unsigned long long ull;
typedef __attribute__((ext_vector_type(8))) short s16x8;
typedef __attribute__((ext_vector_type(8))) unsigned short u16x8;
typedef __attribute__((ext_vector_type(4))) float f32x4;

// Problem constants
#define TT 256
#define BB 32
#define VV 4712
#define HH 500
#define FOURH 2000
#define MPRE 8160          // 255*32

// ---------------- workspace layout (float offsets) ----------------
#define OFF_DECPRE 16320000
#define OFF_HA     33100000
#define OFF_HB     33120000
#define OFF_FLAGS  33140000
#define OFF_DECH   38449920
#define OFF_NLL    42561920

__device__ __forceinline__ unsigned short f2b(float f) {
  unsigned int b = __float_as_uint(f);
  b = b + 0x7fffu + ((b >> 16) & 1u);   // round-to-nearest-even bf16
  return (unsigned short)(b >> 16);
}

// ---------------- bf16 MFMA GEMM (unchanged from r6) --------------------------
__global__ __launch_bounds__(256) void gemm_bf16(
    const float* __restrict__ A, int lda,
    const float* __restrict__ W, int ldw, int rowmapW,
    int bias_mode, const float* __restrict__ b0, const float* __restrict__ b1,
    float* __restrict__ C, int ldc, int M, int N, int K) {
  __shared__ __align__(16) unsigned short As[128 * 40];
  __shared__ __align__(16) unsigned short Bs[128 * 40];

  const int tid = threadIdx.x;
  const int lane = tid & 63, wid = tid >> 6;
  const int wm = wid >> 1, wn = wid & 1;
  const int row16 = lane & 15, kq = lane >> 4;
  const int m0 = blockIdx.x * 128, n0 = blockIdx.y * 128;

  const int sr = tid >> 1;
  const int ks = (tid & 1) << 4;
  int am = m0 + sr; if (am >= M) am = M - 1;
  const float* arow = A + (long)am * lda;
  int nn = n0 + sr; if (nn >= N) nn = N - 1;
  int rn = nn;
  if (rowmapW) { int t = nn >> 5, b = nn & 31; rn = ((255 - t) << 5) + b; }
  const float* wrow = W + (long)rn * ldw;

  f32x4 acc[4][4];
#pragma unroll
  for (int i = 0; i < 4; ++i)
#pragma unroll
    for (int j = 0; j < 4; ++j) acc[i][j] = (f32x4){0.f, 0.f, 0.f, 0.f};

  const int KT = (K + 31) >> 5;
  for (int kt = 0; kt < KT; ++kt) {
    const int kb = kt * 32 + ks;
    float4 av[4], wv[4];
#pragma unroll
    for (int q = 0; q < 4; ++q) {
      const int k = kb + q * 4;
      if (k < K) {
        av[q] = *(const float4*)(arow + k);
        wv[q] = *(const float4*)(wrow + k);
      } else {
        av[q] = make_float4(0.f, 0.f, 0.f, 0.f);
        wv[q] = make_float4(0.f, 0.f, 0.f, 0.f);
      }
    }
    const u16x8 pa0 = {f2b(av[0].x), f2b(av[0].y), f2b(av[0].z), f2b(av[0].w),
                       f2b(av[1].x), f2b(av[1].y), f2b(av[1].z), f2b(av[1].w)};
    const u16x8 pa1 = {f2b(av[2].x), f2b(av[2].y), f2b(av[2].z), f2b(av[2].w),
                       f2b(av[3].x), f2b(av[3].y), f2b(av[3].z), f2b(av[3].w)};
    const u16x8 pw0 = {f2b(wv[0].x), f2b(wv[0].y), f2b(wv[0].z), f2b(wv[0].w),
                       f2b(wv[1].x), f2b(wv[1].y), f2b(wv[1].z), f2b(wv[1].w)};
    const u16x8 pw1 = {f2b(wv[2].x), f2b(wv[2].y), f2b(wv[2].z), f2b(wv[2].w),
                       f2b(wv[3].x), f2b(wv[3].y), f2b(wv[3].z), f2b(wv[3].w)};

    __syncthreads();
    *(u16x8*)&As[sr * 40 + ks + 0] = pa0;
    *(u16x8*)&As[sr * 40 + ks + 8] = pa1;
    *(u16x8*)&Bs[sr * 40 + ks + 0] = pw0;
    *(u16x8*)&Bs[sr * 40 + ks + 8] = pw1;
    __syncthreads();

    s16x8 afrag[4], bfrag[4];
#pragma unroll
    for (int i = 0; i < 4; ++i)
      afrag[i] = *(const s16x8*)&As[(wm * 64 + i * 16 + row16) * 40 + kq * 8];
#pragma unroll
    for (int j = 0; j < 4; ++j)
      bfrag[j] = *(const s16x8*)&Bs[(wn * 64 + j * 16 + row16) * 40 + kq * 8];
#pragma unroll
    for (int i = 0; i < 4; ++i)
#pragma unroll
      for (int j = 0; j < 4; ++j)
        acc[i][j] = __builtin_amdgcn_mfma_f32_16x16x32_bf16(
            afrag[i], bfrag[j], acc[i][j], 0, 0, 0);
  }

#pragma unroll
  for (int i = 0; i < 4; ++i) {
    const int rbase = m0 + wm * 64 + i * 16 + kq * 4;
#pragma unroll
    for (int r = 0; r < 4; ++r) {
      const int mrow = rbase + r;
      if (mrow < M) {
        const float rb = (bias_mode == 1) ? (b0[mrow] + b1[mrow]) : 0.0f;
        float* crow = C + (long)mrow * ldc;
#pragma unroll
        for (int j = 0; j < 4; ++j) {
          const int col = n0 + wn * 64 + j * 16 + row16;
          if (col < N) {
            float v = acc[i][j][r] + rb;
            if (bias_mode == 0 && b0) v += b0[col];
            crow[col] = v;
          }
        }
      }
    }
  }
}

// ---------------- persistent LSTM recurrence: MFMA inner step -----------------
// Grid 256 = 32 unit-tiles (16 units) x 8 batch groups (4 cols). Whh slice lives
// in REGISTERS as 16 bf16 MFMA A-fragments per wave (rows = q*4+gate so one
// lane's 4 acc regs = the 4 gates of one (unit,batch)). Per step: gather h
// (4x8B IC atomics/thread) -> bf16 LDS [4][544] -> 16 MFMA/wave -> gate
// nonlinearity in-lane (no shuffles) -> store h -> 32-block group barrier.
#define PITCH_H 544
__global__ __launch_bounds__(256) void lstm_rec(
    const float* __restrict__ enc_preT, const float* __restrict__ dec_preT,
    const float* __restrict__ enc_Whh, const float* __restrict__ dec_Whh,
    float* __restrict__ h_a, float* __restrict__ h_b,
    float* __restrict__ dec_h, unsigned* __restrict__ flags) {
  __shared__ __align__(16) unsigned short hb16[4 * PITCH_H];  // 4.25 KB

  const int tid = threadIdx.x;
  const int lane = tid & 63, w = tid >> 6;
  const int kq = lane >> 4;             // 0..3
  const int X = blockIdx.x & 31, Y = blockIdx.x >> 5;
  const int u0 = X * 16, b0 = Y * 4;
  unsigned* gflags = flags + Y * 64;

  // ---- A-fragment row mapping: A/C row rr = q*4 + gate ----
  const int arr = lane & 15;            // A row supplied by this lane
  const int ag  = arr & 3;              // gate of that row
  const int au  = u0 + w * 4 + (arr >> 2);
  const bool auok = (au < 500);

  // ---- output mapping (C): col = lane&15, row = kq*4 + reg ----
  const int c    = lane & 15;           // batch col (active if <4)
  const int uout = u0 + w * 4 + kq;     // unit of this lane's acc regs
  const bool act = (c < 4) && (uout < 500);
  // pre-activation offsets for the 4 gates of (uout, b0+c)
  long preoff[4];
#pragma unroll
  for (int g = 0; g < 4; ++g)
    preoff[g] = (long)(g * 500 + (act ? uout : 0)) * MPRE + b0 + (act ? c : 0);

  // zero k-pads of hb16 (k=500..543; A is zero there too, but avoid NaN*0)
  if (tid < 176) {
    const int cc = tid / 44, k = 500 + tid % 44;
    hb16[cc * PITCH_H + k] = 0;
  }

  float creg = 0.0f;   // cell state (uout, b0+c) on active lanes

  const float* pres[2] = {enc_preT, dec_preT};
  const float* whhs[2] = {enc_Whh, dec_Whh};
  float* hcur = h_a;
  float* hnxt = h_b;
  unsigned step = 0;

  for (int ph = 0; ph < 2; ++ph) {
    const float* pre = pres[ph];
    const float* Whh = whhs[ph];

    // ---- load Whh slice into A-fragments (once per phase) ----
    s16x8 afrag[16];
    {
      const float* wrow = Whh + (long)(ag * 500 + (auok ? au : 0)) * 500;
#pragma unroll
      for (int ch = 0; ch < 16; ++ch) {
        const int k0 = ch * 32 + kq * 8;
        float4 v0 = make_float4(0.f, 0.f, 0.f, 0.f);
        float4 v1 = make_float4(0.f, 0.f, 0.f, 0.f);
        if (auok && k0 < 500)     v0 = *(const float4*)(wrow + k0);
        if (auok && k0 + 4 < 500) v1 = *(const float4*)(wrow + k0 + 4);
        const u16x8 p = {f2b(v0.x), f2b(v0.y), f2b(v0.z), f2b(v0.w),
                         f2b(v1.x), f2b(v1.y), f2b(v1.z), f2b(v1.w)};
        afrag[ch] = (s16x8)p;
      }
    }

    for (int t = 0; t < 255; ++t) {
      // pre-activations for this lane's 4 gates (independent of h, issue early)
      float pv[4];
#pragma unroll
      for (int g = 0; g < 4; ++g) pv[g] = pre[preoff[g] + t * 32];

      // gather h[:, b0..b0+3] (1000 x 8B relaxed IC atomics), convert to bf16
      {
        const ull* src = (const ull*)hcur;
        for (int idx = tid; idx < 1000; idx += 256) {
          const int uu = idx >> 1, e = idx & 1;
          const ull v = __hip_atomic_load(&src[uu * 16 + (b0 >> 1) + e],
                                          __ATOMIC_RELAXED,
                                          __HIP_MEMORY_SCOPE_AGENT);
          union { ull q; float f[2]; } cv; cv.q = v;
          hb16[(2 * e + 0) * PITCH_H + uu] = f2b(cv.f[0]);
          hb16[(2 * e + 1) * PITCH_H + uu] = f2b(cv.f[1]);
        }
      }
      __syncthreads();

      // 16 MFMA: acc[reg g] = gate-g pre-activation of (uout, b0+c)
      f32x4 acc = (f32x4){0.f, 0.f, 0.f, 0.f};
      const unsigned short* hbase = &hb16[(c & 3) * PITCH_H + kq * 8];
#pragma unroll
      for (int ch = 0; ch < 16; ++ch) {
        const s16x8 bfrag = *(const s16x8*)(hbase + ch * 32);
        acc = __builtin_amdgcn_mfma_f32_16x16x32_bf16(afrag[ch], bfrag, acc,
                                                      0, 0, 0);
      }

      if (act) {
        const float iv = acc[0] + pv[0];
        const float fv = acc[1] + pv[1];
        const float gv = acc[2] + pv[2];
        const float ov = acc[3] + pv[3];
        const float si = 1.0f / (1.0f + expf(-iv));
        const float sf = 1.0f / (1.0f + expf(-fv));
        const float so = 1.0f / (1.0f + expf(-ov));
        const float cn = sf * creg + si * tanhf(gv);
        const float hn = so * tanhf(cn);
        creg = cn;
        __hip_atomic_store(&hnxt[uout * 32 + b0 + c], hn, __ATOMIC_RELAXED,
                           __HIP_MEMORY_SCOPE_AGENT);
        if (ph == 1)
          __hip_atomic_store(&dec_h[(long)(t * 32 + b0 + c) * 500 + uout], hn,
                             __ATOMIC_RELAXED, __HIP_MEMORY_SCOPE_AGENT);
      }

      ++step;
      // group barrier: syncthreads drains vmcnt (h stores ACKed at IC),
      // release-publish own flag, poll the 31 peers, resync.
      __syncthreads();
      if (tid == 0)
        __hip_atomic_store(&gflags[X], step, __ATOMIC_RELEASE,
                           __HIP_MEMORY_SCOPE_AGENT);
      if (tid < 32 && tid != X) {
        while (__hip_atomic_load(&gflags[tid], __ATOMIC_RELAXED,
                                 __HIP_MEMORY_SCOPE_AGENT) < step) {
          __builtin_amdgcn_s_sleep(1);
        }
      }
      __syncthreads();
      float* tmpp = hcur; hcur = hnxt; hnxt = tmpp;
    }
  }
}

// ---------------- per-row log-softmax NLL ----------------
__device__ __forceinline__ float wave_max(float v) {
#pragma unroll
  for (int o = 32; o > 0; o >>= 1) v = fmaxf(v, __shfl_xor(v, o, 64));
  return v;
}
__device__ __forceinline__ float wave_sum(float v) {
#pragma unroll
  for (int o = 32; o > 0; o >>= 1) v += __shfl_xor(v, o, 64);
  return v;
}

__global__ __launch_bounds__(256) void loss_rows(
    const float* __restrict__ seq, const float* __restrict__ logits,
    const int* __restrict__ nseq, float* __restrict__ nll) {
  __shared__ float sm[8];
  const int r = blockIdx.x, tid = threadIdx.x;
  const int t = r >> 5, b = r & 31;
  const float* row = (t == 0) ? (seq + (long)b * VV)
                              : (logits + (long)((t - 1) * 32 + b) * VV);
  float m = -INFINITY;
  for (int c = tid; c < 1178; c += 256) {
    float4 v = *(const float4*)&row[c * 4];
    m = fmaxf(m, fmaxf(fmaxf(v.x, v.y), fmaxf(v.z, v.w)));
  }
  m = wave_max(m);
  const int wid = tid >> 6;
  if ((tid & 63) == 0) sm[wid] = m;
  __syncthreads();
  const float M4 = fmaxf(fmaxf(sm[0], sm[1]), fmaxf(sm[2], sm[3]));
  float s = 0.0f;
  for (int c = tid; c < 1178; c += 256) {
    float4 v = *(const float4*)&row[c * 4];
    s += expf(v.x - M4) + expf(v.y - M4) + expf(v.z - M4) + expf(v.w - M4);
  }
  s = wave_sum(s);
  if ((tid & 63) == 0) sm[4 + wid] = s;
  __syncthreads();
  if (tid == 0) {
    const float S = sm[4] + sm[5] + sm[6] + sm[7];
    const int tgt = nseq[(t << 5) + b];
    nll[r] = M4 + logf(S) - row[tgt];
  }
}

__global__ __launch_bounds__(256) void final_reduce(
    const float* __restrict__ nll, float* __restrict__ out) {
  __shared__ float sm[4];
  float s = 0.0f;
  for (int c = threadIdx.x; c < 8192; c += 256) s += nll[c];
  s = wave_sum(s);
  if ((threadIdx.x & 63) == 0) sm[threadIdx.x >> 6] = s;
  __syncthreads();
  if (threadIdx.x == 0) out[0] = (sm[0] + sm[1] + sm[2] + sm[3]) * (1.0f / 8192.0f);
}

// ---------------- launch ----------------
extern "C" void kernel_launch(void* const* d_in, const int* in_sizes, int n_in,
                              void* d_out, int out_size, void* d_ws, size_t ws_size,
                              hipStream_t stream) {
  (void)in_sizes; (void)n_in; (void)out_size; (void)ws_size;
  const float* seq  = (const float*)d_in[0];
  const int* nseq   = (const int*)d_in[1];
  const float* eWih = (const float*)d_in[2];
  const float* eWhh = (const float*)d_in[3];
  const float* ebih = (const float*)d_in[4];
  const float* ebhh = (const float*)d_in[5];
  const float* dWih = (const float*)d_in[6];
  const float* dWhh = (const float*)d_in[7];
  const float* dbih = (const float*)d_in[8];
  const float* dbhh = (const float*)d_in[9];
  const float* oW   = (const float*)d_in[10];
  const float* ob   = (const float*)d_in[11];

  float* wsf = (float*)d_ws;
  float* logits   = wsf;
  float* enc_preT = wsf;
  float* dec_preT = wsf + OFF_DECPRE;
  float* h_a      = wsf + OFF_HA;
  float* h_b      = wsf + OFF_HB;
  float* dec_h    = wsf + OFF_DECH;
  float* nll      = wsf + OFF_NLL;
  unsigned* flags = (unsigned*)(wsf + OFF_FLAGS);

  hipMemsetAsync(h_a, 0, 16384 * sizeof(float), stream);
  hipMemsetAsync(h_b, 0, 16384 * sizeof(float), stream);
  hipMemsetAsync(flags, 0, 512 * sizeof(unsigned), stream);

  dim3 blk(256);
  // enc_preT[j][t*32+b] = eWih[j,:] . seq[(255-t)*32+b,:] + ebih[j]+ebhh[j]
  gemm_bf16<<<dim3(16, 64), blk, 0, stream>>>(eWih, VV, seq, VV, 1,
                                              1, ebih, ebhh,
                                              enc_preT, MPRE, FOURH, MPRE, VV);
  // dec_preT[j][t*32+b] = dWih[j,:] . seq[t*32+b,:] + dbih[j]+dbhh[j]
  gemm_bf16<<<dim3(16, 64), blk, 0, stream>>>(dWih, VV, seq, VV, 0,
                                              1, dbih, dbhh,
                                              dec_preT, MPRE, FOURH, MPRE, VV);
  // recurrence (encoder then decoder), writes dec_h
  lstm_rec<<<dim3(256), blk, 0, stream>>>(enc_preT, dec_preT, eWhh, dWhh,
                                          h_a, h_b, dec_h, flags);
  // logits = dec_h @ out_W^T + out_b  (overwrites preT buffers; dec_h disjoint)
  gemm_bf16<<<dim3(64, 37), blk, 0, stream>>>(dec_h, HH, oW, HH, 0,
                                              0, ob, nullptr,
                                              logits, VV, MPRE, VV, HH);
  // per-row NLL then deterministic reduce
  loss_rows<<<dim3(8192), blk, 0, stream>>>(seq, logits, nseq, nll);
  final_reduce<<<dim3(1), blk, 0, stream>>>(nll, (float*)d_out);
}

// Round 8
// 4573.729 us; speedup vs baseline: 6.1804x; 1.1018x over previous
//
#include <hip/hip_runtime.h>
#include <math.h>

typedef unsigned long long ull;
typedef __attribute__((ext_vector_type(8))) short s16x8;
typedef __attribute__((ext_vector_type(8))) unsigned short u16x8;
typedef __attribute__((ext_vector_type(4))) float f32x4;

// Problem constants
#define TT 256
#define BB 32
#define VV 4712
#define HH 500
#define FOURH 2000
#define MPRE 8160          // 255*32

// ---------------- workspace layout (float offsets) ----------------
// logits   : 0 .. 38,449,920 (8160*4712)
//   enc_preT: 0 .. 16,320,000            overlaps logits
//   dec_preT: 16,320,000 .. 32,640,000   overlaps logits
//   hring   : 33,100,000 .. 33,198,304   (3 rings x 16384 x 8B tagged slots)
// dec_h    : 38,449,920 .. 42,529,920
// nll      : 42,561,920 .. 42,570,112
#define OFF_DECPRE 16320000
#define OFF_HR     33100000
#define OFF_DECH   38449920
#define OFF_NLL    42561920
#define RING_SLOTS 16384

__device__ __forceinline__ unsigned short f2b(float f) {
  unsigned int b = __float_as_uint(f);
  b = b + 0x7fffu + ((b >> 16) & 1u);   // round-to-nearest-even bf16
  return (unsigned short)(b >> 16);
}

// ---------------- bf16 MFMA GEMM (unchanged from r6/r7) -----------------------
__global__ __launch_bounds__(256) void gemm_bf16(
    const float* __restrict__ A, int lda,
    const float* __restrict__ W, int ldw, int rowmapW,
    int bias_mode, const float* __restrict__ b0, const float* __restrict__ b1,
    float* __restrict__ C, int ldc, int M, int N, int K) {
  __shared__ __align__(16) unsigned short As[128 * 40];
  __shared__ __align__(16) unsigned short Bs[128 * 40];

  const int tid = threadIdx.x;
  const int lane = tid & 63, wid = tid >> 6;
  const int wm = wid >> 1, wn = wid & 1;
  const int row16 = lane & 15, kq = lane >> 4;
  const int m0 = blockIdx.x * 128, n0 = blockIdx.y * 128;

  const int sr = tid >> 1;
  const int ks = (tid & 1) << 4;
  int am = m0 + sr; if (am >= M) am = M - 1;
  const float* arow = A + (long)am * lda;
  int nn = n0 + sr; if (nn >= N) nn = N - 1;
  int rn = nn;
  if (rowmapW) { int t = nn >> 5, b = nn & 31; rn = ((255 - t) << 5) + b; }
  const float* wrow = W + (long)rn * ldw;

  f32x4 acc[4][4];
#pragma unroll
  for (int i = 0; i < 4; ++i)
#pragma unroll
    for (int j = 0; j < 4; ++j) acc[i][j] = (f32x4){0.f, 0.f, 0.f, 0.f};

  const int KT = (K + 31) >> 5;
  for (int kt = 0; kt < KT; ++kt) {
    const int kb = kt * 32 + ks;
    float4 av[4], wv[4];
#pragma unroll
    for (int q = 0; q < 4; ++q) {
      const int k = kb + q * 4;
      if (k < K) {
        av[q] = *(const float4*)(arow + k);
        wv[q] = *(const float4*)(wrow + k);
      } else {
        av[q] = make_float4(0.f, 0.f, 0.f, 0.f);
        wv[q] = make_float4(0.f, 0.f, 0.f, 0.f);
      }
    }
    const u16x8 pa0 = {f2b(av[0].x), f2b(av[0].y), f2b(av[0].z), f2b(av[0].w),
                       f2b(av[1].x), f2b(av[1].y), f2b(av[1].z), f2b(av[1].w)};
    const u16x8 pa1 = {f2b(av[2].x), f2b(av[2].y), f2b(av[2].z), f2b(av[2].w),
                       f2b(av[3].x), f2b(av[3].y), f2b(av[3].z), f2b(av[3].w)};
    const u16x8 pw0 = {f2b(wv[0].x), f2b(wv[0].y), f2b(wv[0].z), f2b(wv[0].w),
                       f2b(wv[1].x), f2b(wv[1].y), f2b(wv[1].z), f2b(wv[1].w)};
    const u16x8 pw1 = {f2b(wv[2].x), f2b(wv[2].y), f2b(wv[2].z), f2b(wv[2].w),
                       f2b(wv[3].x), f2b(wv[3].y), f2b(wv[3].z), f2b(wv[3].w)};

    __syncthreads();
    *(u16x8*)&As[sr * 40 + ks + 0] = pa0;
    *(u16x8*)&As[sr * 40 + ks + 8] = pa1;
    *(u16x8*)&Bs[sr * 40 + ks + 0] = pw0;
    *(u16x8*)&Bs[sr * 40 + ks + 8] = pw1;
    __syncthreads();

    s16x8 afrag[4], bfrag[4];
#pragma unroll
    for (int i = 0; i < 4; ++i)
      afrag[i] = *(const s16x8*)&As[(wm * 64 + i * 16 + row16) * 40 + kq * 8];
#pragma unroll
    for (int j = 0; j < 4; ++j)
      bfrag[j] = *(const s16x8*)&Bs[(wn * 64 + j * 16 + row16) * 40 + kq * 8];
#pragma unroll
    for (int i = 0; i < 4; ++i)
#pragma unroll
      for (int j = 0; j < 4; ++j)
        acc[i][j] = __builtin_amdgcn_mfma_f32_16x16x32_bf16(
            afrag[i], bfrag[j], acc[i][j], 0, 0, 0);
  }

#pragma unroll
  for (int i = 0; i < 4; ++i) {
    const int rbase = m0 + wm * 64 + i * 16 + kq * 4;
#pragma unroll
    for (int r = 0; r < 4; ++r) {
      const int mrow = rbase + r;
      if (mrow < M) {
        const float rb = (bias_mode == 1) ? (b0[mrow] + b1[mrow]) : 0.0f;
        float* crow = C + (long)mrow * ldc;
#pragma unroll
        for (int j = 0; j < 4; ++j) {
          const int col = n0 + wn * 64 + j * 16 + row16;
          if (col < N) {
            float v = acc[i][j][r] + rb;
            if (bias_mode == 0 && b0) v += b0[col];
            crow[col] = v;
          }
        }
      }
    }
  }
}

// ---------------- persistent LSTM recurrence: tagged-ring exchange ------------
// Grid 256 = 32 unit-tiles x 8 independent batch groups. Whh in registers as 16
// MFMA A-frags. Cross-block h exchange: each h value is an 8B atomic
// {f32 value | u32 step-tag} in a 3-deep ring (step%3). Producers store value
// and tag in ONE relaxed IC atomic; consumers poll the 2000 slots their group
// needs until tag >= step-1. No flags, no grid barrier, no fences: one IC
// visibility hop per step. Ring depth 3 is sufficient: a block can lead the
// slowest by at most 1 step (it needs all tag-(s-1) values to produce tag-s),
// so the (s)%3 write never collides with (s-1)%3 readers, and (s+2)%3 reuse
// is fully drained. hb16 double-buffered -> single __syncthreads per step.
#define PITCH_H 544
__global__ __launch_bounds__(256) void lstm_rec(
    const float* __restrict__ enc_preT, const float* __restrict__ dec_preT,
    const float* __restrict__ enc_Whh, const float* __restrict__ dec_Whh,
    ull* __restrict__ hring, float* __restrict__ dec_h) {
  __shared__ __align__(16) unsigned short hb16[2][4 * PITCH_H];  // 8.5 KB

  const int tid = threadIdx.x;
  const int lane = tid & 63, w = tid >> 6;
  const int kq = lane >> 4;             // 0..3
  const int X = blockIdx.x & 31, Y = blockIdx.x >> 5;
  const int u0 = X * 16, b0 = Y * 4;

  // ---- A-fragment row mapping: A/C row rr = q*4 + gate ----
  const int arr = lane & 15;
  const int ag  = arr & 3;
  const int au  = u0 + w * 4 + (arr >> 2);
  const bool auok = (au < 500);

  // ---- output mapping (C): col = lane&15, row = kq*4 + reg ----
  const int c    = lane & 15;           // batch col (active if <4)
  const int uout = u0 + w * 4 + kq;
  const bool act = (c < 4) && (uout < 500);
  long preoff[4];
#pragma unroll
  for (int g = 0; g < 4; ++g)
    preoff[g] = (long)(g * 500 + (act ? uout : 0)) * MPRE + b0 + (act ? c : 0);

  // zero k-pads of both hb16 buffers (k=500..543)
  if (tid < 352) {
    const int bq = tid / 176, rr = tid % 176;
    const int cc = rr / 44, k = 500 + rr % 44;
    hb16[bq][cc * PITCH_H + k] = 0;
  }
  __syncthreads();

  float creg = 0.0f;   // cell state (uout, b0+c) on active lanes

  const float* pres[2] = {enc_preT, dec_preT};
  const float* whhs[2] = {enc_Whh, dec_Whh};
  unsigned step = 0;   // global step 1..510 across both phases

  for (int ph = 0; ph < 2; ++ph) {
    const float* pre = pres[ph];
    const float* Whh = whhs[ph];

    // ---- load Whh slice into A-fragments (once per phase) ----
    s16x8 afrag[16];
    {
      const float* wrow = Whh + (long)(ag * 500 + (auok ? au : 0)) * 500;
#pragma unroll
      for (int ch = 0; ch < 16; ++ch) {
        const int k0 = ch * 32 + kq * 8;
        float4 v0 = make_float4(0.f, 0.f, 0.f, 0.f);
        float4 v1 = make_float4(0.f, 0.f, 0.f, 0.f);
        if (auok && k0 < 500)     v0 = *(const float4*)(wrow + k0);
        if (auok && k0 + 4 < 500) v1 = *(const float4*)(wrow + k0 + 4);
        const u16x8 p = {f2b(v0.x), f2b(v0.y), f2b(v0.z), f2b(v0.w),
                         f2b(v1.x), f2b(v1.y), f2b(v1.z), f2b(v1.w)};
        afrag[ch] = (s16x8)p;
      }
    }

    for (int t = 0; t < 255; ++t) {
      ++step;
      const unsigned want = step - 1;
      const int buf = step & 1;
      const ull* rring = hring + (ull)((step - 1) % 3) * RING_SLOTS;
      ull* wring = hring + (ull)(step % 3) * RING_SLOTS;

      // pre-activations for this lane's 4 gates (independent, issue early)
      float pv[4];
#pragma unroll
      for (int g = 0; g < 4; ++g) pv[g] = pre[preoff[g] + t * 32];

      // poll-gather the 2000 tagged slots this group needs (8 per thread)
      // gi = tid + j*256 -> (uu = gi>>2, c = gi&3), slot = uu*32 + b0 + c
      unsigned pend = (tid < 208) ? 0xffu : 0x7fu;
      ull vals[8];
      while (pend) {
        unsigned np = pend;
#pragma unroll
        for (int j = 0; j < 8; ++j) {
          if (np & (1u << j)) {
            const int gi = tid + j * 256;
            const ull v = __hip_atomic_load(
                &rring[((gi >> 2) << 5) + b0 + (gi & 3)],
                __ATOMIC_RELAXED, __HIP_MEMORY_SCOPE_AGENT);
            if ((unsigned)(v >> 32) >= want) { vals[j] = v; np &= ~(1u << j); }
          }
        }
        pend = np;
        if (pend) __builtin_amdgcn_s_sleep(1);
      }
#pragma unroll
      for (int j = 0; j < 8; ++j) {
        const int gi = tid + j * 256;
        if (gi < 2000)
          hb16[buf][(gi & 3) * PITCH_H + (gi >> 2)] =
              f2b(__uint_as_float((unsigned)(vals[j] & 0xffffffffu)));
      }
      __syncthreads();

      // 16 MFMA: acc reg g = gate-g recurrent term of (uout, b0+c)
      f32x4 acc = (f32x4){0.f, 0.f, 0.f, 0.f};
      const unsigned short* hbase = &hb16[buf][(c & 3) * PITCH_H + kq * 8];
#pragma unroll
      for (int ch = 0; ch < 16; ++ch) {
        const s16x8 bfrag = *(const s16x8*)(hbase + ch * 32);
        acc = __builtin_amdgcn_mfma_f32_16x16x32_bf16(afrag[ch], bfrag, acc,
                                                      0, 0, 0);
      }

      if (act) {
        const float iv = acc[0] + pv[0];
        const float fv = acc[1] + pv[1];
        const float gv = acc[2] + pv[2];
        const float ov = acc[3] + pv[3];
        const float si = 1.0f / (1.0f + expf(-iv));
        const float sf = 1.0f / (1.0f + expf(-fv));
        const float so = 1.0f / (1.0f + expf(-ov));
        const float cn = sf * creg + si * tanhf(gv);
        const float hn = so * tanhf(cn);
        creg = cn;
        // publish value+tag in one atomic: the data IS the flag
        __hip_atomic_store(&wring[(uout << 5) + b0 + c],
                           ((ull)step << 32) | __float_as_uint(hn),
                           __ATOMIC_RELAXED, __HIP_MEMORY_SCOPE_AGENT);
        if (ph == 1)
          dec_h[(long)(t * 32 + b0 + c) * 500 + uout] = hn;
      }
      // no barrier: next step polls the ring; hb16 double-buffer + the single
      // __syncthreads above bound intra-block wave skew to one step.
    }
  }
}

// ---------------- per-row log-softmax NLL ----------------
__device__ __forceinline__ float wave_max(float v) {
#pragma unroll
  for (int o = 32; o > 0; o >>= 1) v = fmaxf(v, __shfl_xor(v, o, 64));
  return v;
}
__device__ __forceinline__ float wave_sum(float v) {
#pragma unroll
  for (int o = 32; o > 0; o >>= 1) v += __shfl_xor(v, o, 64);
  return v;
}

__global__ __launch_bounds__(256) void loss_rows(
    const float* __restrict__ seq, const float* __restrict__ logits,
    const int* __restrict__ nseq, float* __restrict__ nll) {
  __shared__ float sm[8];
  const int r = blockIdx.x, tid = threadIdx.x;
  const int t = r >> 5, b = r & 31;
  const float* row = (t == 0) ? (seq + (long)b * VV)
                              : (logits + (long)((t - 1) * 32 + b) * VV);
  float m = -INFINITY;
  for (int c = tid; c < 1178; c += 256) {
    float4 v = *(const float4*)&row[c * 4];
    m = fmaxf(m, fmaxf(fmaxf(v.x, v.y), fmaxf(v.z, v.w)));
  }
  m = wave_max(m);
  const int wid = tid >> 6;
  if ((tid & 63) == 0) sm[wid] = m;
  __syncthreads();
  const float M4 = fmaxf(fmaxf(sm[0], sm[1]), fmaxf(sm[2], sm[3]));
  float s = 0.0f;
  for (int c = tid; c < 1178; c += 256) {
    float4 v = *(const float4*)&row[c * 4];
    s += expf(v.x - M4) + expf(v.y - M4) + expf(v.z - M4) + expf(v.w - M4);
  }
  s = wave_sum(s);
  if ((tid & 63) == 0) sm[4 + wid] = s;
  __syncthreads();
  if (tid == 0) {
    const float S = sm[4] + sm[5] + sm[6] + sm[7];
    const int tgt = nseq[(t << 5) + b];
    nll[r] = M4 + logf(S) - row[tgt];
  }
}

__global__ __launch_bounds__(256) void final_reduce(
    const float* __restrict__ nll, float* __restrict__ out) {
  __shared__ float sm[4];
  float s = 0.0f;
  for (int c = threadIdx.x; c < 8192; c += 256) s += nll[c];
  s = wave_sum(s);
  if ((threadIdx.x & 63) == 0) sm[threadIdx.x >> 6] = s;
  __syncthreads();
  if (threadIdx.x == 0) out[0] = (sm[0] + sm[1] + sm[2] + sm[3]) * (1.0f / 8192.0f);
}

// ---------------- launch ----------------
extern "C" void kernel_launch(void* const* d_in, const int* in_sizes, int n_in,
                              void* d_out, int out_size, void* d_ws, size_t ws_size,
                              hipStream_t stream) {
  (void)in_sizes; (void)n_in; (void)out_size; (void)ws_size;
  const float* seq  = (const float*)d_in[0];
  const int* nseq   = (const int*)d_in[1];
  const float* eWih = (const float*)d_in[2];
  const float* eWhh = (const float*)d_in[3];
  const float* ebih = (const float*)d_in[4];
  const float* ebhh = (const float*)d_in[5];
  const float* dWih = (const float*)d_in[6];
  const float* dWhh = (const float*)d_in[7];
  const float* dbih = (const float*)d_in[8];
  const float* dbhh = (const float*)d_in[9];
  const float* oW   = (const float*)d_in[10];
  const float* ob   = (const float*)d_in[11];

  float* wsf = (float*)d_ws;
  float* logits   = wsf;
  float* enc_preT = wsf;
  float* dec_preT = wsf + OFF_DECPRE;
  ull*   hring    = (ull*)(wsf + OFF_HR);
  float* dec_h    = wsf + OFF_DECH;
  float* nll      = wsf + OFF_NLL;

  // rings: {f32 0.0 | tag 0} everywhere; ring0 tag0 == initial h^0 (want=0)
  hipMemsetAsync(hring, 0, 3 * RING_SLOTS * sizeof(ull), stream);

  dim3 blk(256);
  // enc_preT[j][t*32+b] = eWih[j,:] . seq[(255-t)*32+b,:] + ebih[j]+ebhh[j]
  gemm_bf16<<<dim3(16, 64), blk, 0, stream>>>(eWih, VV, seq, VV, 1,
                                              1, ebih, ebhh,
                                              enc_preT, MPRE, FOURH, MPRE, VV);
  // dec_preT[j][t*32+b] = dWih[j,:] . seq[t*32+b,:] + dbih[j]+dbhh[j]
  gemm_bf16<<<dim3(16, 64), blk, 0, stream>>>(dWih, VV, seq, VV, 0,
                                              1, dbih, dbhh,
                                              dec_preT, MPRE, FOURH, MPRE, VV);
  // recurrence (encoder then decoder), writes dec_h
  lstm_rec<<<dim3(256), blk, 0, stream>>>(enc_preT, dec_preT, eWhh, dWhh,
                                          hring, dec_h);
  // logits = dec_h @ out_W^T + out_b  (overwrites preT buffers; dec_h disjoint)
  gemm_bf16<<<dim3(64, 37), blk, 0, stream>>>(dec_h, HH, oW, HH, 0,
                                              0, ob, nullptr,
                                              logits, VV, MPRE, VV, HH);
  // per-row NLL then deterministic reduce
  loss_rows<<<dim3(8192), blk, 0, stream>>>(seq, logits, nseq, nll);
  final_reduce<<<dim3(1), blk, 0, stream>>>(nll, (float*)d_out);
}

// Round 10
// 4540.660 us; speedup vs baseline: 6.2254x; 1.0073x over previous
//
#include <hip/hip_runtime.h>
#include <math.h>

typedef unsigned long long ull;
typedef __attribute__((ext_vector_type(8))) short s16x8;
typedef __attribute__((ext_vector_type(8))) unsigned short u16x8;
typedef __attribute__((ext_vector_type(4))) float f32x4;

// Problem constants
#define TT 256
#define BB 32
#define VV 4712
#define HH 500
#define FOURH 2000
#define MPRE 8160          // 255*32

// ---------------- workspace layout (float offsets) ----------------
// logits   : 0 .. 38,449,920 (8160*4712)
//   enc_preT: 0 .. 16,320,000            overlaps logits
//   dec_preT: 16,320,000 .. 32,640,000   overlaps logits
//   hring   : 33,100,000 .. 33,198,304   (3 rings x 16384 x 8B tagged slots)
// dec_h    : 38,449,920 .. 42,529,920
// nll      : 42,561,920 .. 42,570,112
#define OFF_DECPRE 16320000
#define OFF_HR     33100000
#define OFF_DECH   38449920
#define OFF_NLL    42561920
#define RING_SLOTS 16384

__device__ __forceinline__ unsigned short f2b(float f) {
  unsigned int b = __float_as_uint(f);
  b = b + 0x7fffu + ((b >> 16) & 1u);   // round-to-nearest-even bf16
  return (unsigned short)(b >> 16);
}

// ---------------- bf16 MFMA GEMM: r8-proven f2b conversion + dbuf pipeline ----
// 128x128 tile, 4 waves, BK=32, LDS double-buffered (2x20KB). Per iter:
// issue next tile's global loads -> frag reads + MFMA on current buffer
// (loads in flight underneath) -> convert (f2b, r8-identical) + store to the
// other buffer -> ONE barrier. Conversion path unchanged from the verified r8.
__global__ __launch_bounds__(256) void gemm_bf16(
    const float* __restrict__ A, int lda,
    const float* __restrict__ W, int ldw, int rowmapW,
    int bias_mode, const float* __restrict__ b0, const float* __restrict__ b1,
    float* __restrict__ C, int ldc, int M, int N, int K) {
  __shared__ __align__(16) unsigned short As[2][128 * 40];
  __shared__ __align__(16) unsigned short Bs[2][128 * 40];

  const int tid = threadIdx.x;
  const int lane = tid & 63, wid = tid >> 6;
  const int wm = wid >> 1, wn = wid & 1;
  const int row16 = lane & 15, kq = lane >> 4;
  const int m0 = blockIdx.x * 128, n0 = blockIdx.y * 128;

  const int sr = tid >> 1;
  const int ks = (tid & 1) << 4;
  int am = m0 + sr; if (am >= M) am = M - 1;
  const float* arow = A + (long)am * lda;
  int nn = n0 + sr; if (nn >= N) nn = N - 1;
  int rn = nn;
  if (rowmapW) { int t = nn >> 5, b = nn & 31; rn = ((255 - t) << 5) + b; }
  const float* wrow = W + (long)rn * ldw;

  f32x4 acc[4][4];
#pragma unroll
  for (int i = 0; i < 4; ++i)
#pragma unroll
    for (int j = 0; j < 4; ++j) acc[i][j] = (f32x4){0.f, 0.f, 0.f, 0.f};

  float4 av[4], wv[4];

#define LOAD_TILE(kt_)                                                      \
  do {                                                                      \
    const int kb_ = (kt_) * 32 + ks;                                        \
    _Pragma("unroll")                                                       \
    for (int q = 0; q < 4; ++q) {                                           \
      const int k_ = kb_ + q * 4; /* K multiple of 4 in all our calls */    \
      if (k_ < K) {                                                         \
        av[q] = *(const float4*)(arow + k_);                                \
        wv[q] = *(const float4*)(wrow + k_);                                \
      } else {                                                              \
        av[q] = make_float4(0.f, 0.f, 0.f, 0.f);                            \
        wv[q] = make_float4(0.f, 0.f, 0.f, 0.f);                            \
      }                                                                     \
    }                                                                       \
  } while (0)

#define CVT_STORE(bq_)                                                      \
  do {                                                                      \
    const u16x8 pa0 = {f2b(av[0].x), f2b(av[0].y), f2b(av[0].z), f2b(av[0].w), \
                       f2b(av[1].x), f2b(av[1].y), f2b(av[1].z), f2b(av[1].w)}; \
    const u16x8 pa1 = {f2b(av[2].x), f2b(av[2].y), f2b(av[2].z), f2b(av[2].w), \
                       f2b(av[3].x), f2b(av[3].y), f2b(av[3].z), f2b(av[3].w)}; \
    const u16x8 pw0 = {f2b(wv[0].x), f2b(wv[0].y), f2b(wv[0].z), f2b(wv[0].w), \
                       f2b(wv[1].x), f2b(wv[1].y), f2b(wv[1].z), f2b(wv[1].w)}; \
    const u16x8 pw1 = {f2b(wv[2].x), f2b(wv[2].y), f2b(wv[2].z), f2b(wv[2].w), \
                       f2b(wv[3].x), f2b(wv[3].y), f2b(wv[3].z), f2b(wv[3].w)}; \
    *(u16x8*)&As[bq_][sr * 40 + ks + 0] = pa0;                              \
    *(u16x8*)&As[bq_][sr * 40 + ks + 8] = pa1;                              \
    *(u16x8*)&Bs[bq_][sr * 40 + ks + 0] = pw0;                              \
    *(u16x8*)&Bs[bq_][sr * 40 + ks + 8] = pw1;                              \
  } while (0)

  // prologue: tile 0 -> buffer 0
  LOAD_TILE(0);
  CVT_STORE(0);
  __syncthreads();

  const int KT = (K + 31) >> 5;
  for (int kt = 0; kt < KT; ++kt) {
    const int cur = kt & 1;
    const bool more = (kt + 1 < KT);
    if (more) LOAD_TILE(kt + 1);   // issue loads; complete under MFMA below

    s16x8 afrag[4], bfrag[4];
#pragma unroll
    for (int i = 0; i < 4; ++i)
      afrag[i] = *(const s16x8*)&As[cur][(wm * 64 + i * 16 + row16) * 40 + kq * 8];
#pragma unroll
    for (int j = 0; j < 4; ++j)
      bfrag[j] = *(const s16x8*)&Bs[cur][(wn * 64 + j * 16 + row16) * 40 + kq * 8];
#pragma unroll
    for (int i = 0; i < 4; ++i)
#pragma unroll
      for (int j = 0; j < 4; ++j)
        acc[i][j] = __builtin_amdgcn_mfma_f32_16x16x32_bf16(
            afrag[i], bfrag[j], acc[i][j], 0, 0, 0);

    if (more) {
      CVT_STORE(cur ^ 1);          // other buffer; prior reads of it done at
      __syncthreads();             // the previous barrier -> safe
    }
  }
#undef LOAD_TILE
#undef CVT_STORE

#pragma unroll
  for (int i = 0; i < 4; ++i) {
    const int rbase = m0 + wm * 64 + i * 16 + kq * 4;
#pragma unroll
    for (int r = 0; r < 4; ++r) {
      const int mrow = rbase + r;
      if (mrow < M) {
        const float rb = (bias_mode == 1) ? (b0[mrow] + b1[mrow]) : 0.0f;
        float* crow = C + (long)mrow * ldc;
#pragma unroll
        for (int j = 0; j < 4; ++j) {
          const int col = n0 + wn * 64 + j * 16 + row16;
          if (col < N) {
            float v = acc[i][j][r] + rb;
            if (bias_mode == 0 && b0) v += b0[col];
            crow[col] = v;
          }
        }
      }
    }
  }
}

// ---------------- persistent LSTM recurrence: tagged-ring exchange ------------
// (byte-identical logic to r8 — kept frozen for clean attribution)
#define PITCH_H 544
__global__ __launch_bounds__(256) void lstm_rec(
    const float* __restrict__ enc_preT, const float* __restrict__ dec_preT,
    const float* __restrict__ enc_Whh, const float* __restrict__ dec_Whh,
    ull* __restrict__ hring, float* __restrict__ dec_h) {
  __shared__ __align__(16) unsigned short hb16[2][4 * PITCH_H];  // 8.5 KB

  const int tid = threadIdx.x;
  const int lane = tid & 63, w = tid >> 6;
  const int kq = lane >> 4;             // 0..3
  const int X = blockIdx.x & 31, Y = blockIdx.x >> 5;
  const int u0 = X * 16, b0 = Y * 4;

  const int arr = lane & 15;
  const int ag  = arr & 3;
  const int au  = u0 + w * 4 + (arr >> 2);
  const bool auok = (au < 500);

  const int c    = lane & 15;           // batch col (active if <4)
  const int uout = u0 + w * 4 + kq;
  const bool act = (c < 4) && (uout < 500);
  long preoff[4];
#pragma unroll
  for (int g = 0; g < 4; ++g)
    preoff[g] = (long)(g * 500 + (act ? uout : 0)) * MPRE + b0 + (act ? c : 0);

  if (tid < 352) {
    const int bq = tid / 176, rr = tid % 176;
    const int cc = rr / 44, k = 500 + rr % 44;
    hb16[bq][cc * PITCH_H + k] = 0;
  }
  __syncthreads();

  float creg = 0.0f;   // cell state (uout, b0+c) on active lanes

  const float* pres[2] = {enc_preT, dec_preT};
  const float* whhs[2] = {enc_Whh, dec_Whh};
  unsigned step = 0;   // global step 1..510 across both phases

  for (int ph = 0; ph < 2; ++ph) {
    const float* pre = pres[ph];
    const float* Whh = whhs[ph];

    s16x8 afrag[16];
    {
      const float* wrow = Whh + (long)(ag * 500 + (auok ? au : 0)) * 500;
#pragma unroll
      for (int ch = 0; ch < 16; ++ch) {
        const int k0 = ch * 32 + kq * 8;
        float4 v0 = make_float4(0.f, 0.f, 0.f, 0.f);
        float4 v1 = make_float4(0.f, 0.f, 0.f, 0.f);
        if (auok && k0 < 500)     v0 = *(const float4*)(wrow + k0);
        if (auok && k0 + 4 < 500) v1 = *(const float4*)(wrow + k0 + 4);
        const u16x8 p = {f2b(v0.x), f2b(v0.y), f2b(v0.z), f2b(v0.w),
                         f2b(v1.x), f2b(v1.y), f2b(v1.z), f2b(v1.w)};
        afrag[ch] = (s16x8)p;
      }
    }

    for (int t = 0; t < 255; ++t) {
      ++step;
      const unsigned want = step - 1;
      const int buf = step & 1;
      const ull* rring = hring + (ull)((step - 1) % 3) * RING_SLOTS;
      ull* wring = hring + (ull)(step % 3) * RING_SLOTS;

      float pv[4];
#pragma unroll
      for (int g = 0; g < 4; ++g) pv[g] = pre[preoff[g] + t * 32];

      unsigned pend = (tid < 208) ? 0xffu : 0x7fu;
      ull vals[8];
      while (pend) {
        unsigned np = pend;
#pragma unroll
        for (int j = 0; j < 8; ++j) {
          if (np & (1u << j)) {
            const int gi = tid + j * 256;
            const ull v = __hip_atomic_load(
                &rring[((gi >> 2) << 5) + b0 + (gi & 3)],
                __ATOMIC_RELAXED, __HIP_MEMORY_SCOPE_AGENT);
            if ((unsigned)(v >> 32) >= want) { vals[j] = v; np &= ~(1u << j); }
          }
        }
        pend = np;
        if (pend) __builtin_amdgcn_s_sleep(1);
      }
#pragma unroll
      for (int j = 0; j < 8; ++j) {
        const int gi = tid + j * 256;
        if (gi < 2000)
          hb16[buf][(gi & 3) * PITCH_H + (gi >> 2)] =
              f2b(__uint_as_float((unsigned)(vals[j] & 0xffffffffu)));
      }
      __syncthreads();

      f32x4 acc = (f32x4){0.f, 0.f, 0.f, 0.f};
      const unsigned short* hbase = &hb16[buf][(c & 3) * PITCH_H + kq * 8];
#pragma unroll
      for (int ch = 0; ch < 16; ++ch) {
        const s16x8 bfrag = *(const s16x8*)(hbase + ch * 32);
        acc = __builtin_amdgcn_mfma_f32_16x16x32_bf16(afrag[ch], bfrag, acc,
                                                      0, 0, 0);
      }

      if (act) {
        const float iv = acc[0] + pv[0];
        const float fv = acc[1] + pv[1];
        const float gv = acc[2] + pv[2];
        const float ov = acc[3] + pv[3];
        const float si = 1.0f / (1.0f + expf(-iv));
        const float sf = 1.0f / (1.0f + expf(-fv));
        const float so = 1.0f / (1.0f + expf(-ov));
        const float cn = sf * creg + si * tanhf(gv);
        const float hn = so * tanhf(cn);
        creg = cn;
        __hip_atomic_store(&wring[(uout << 5) + b0 + c],
                           ((ull)step << 32) | __float_as_uint(hn),
                           __ATOMIC_RELAXED, __HIP_MEMORY_SCOPE_AGENT);
        if (ph == 1)
          dec_h[(long)(t * 32 + b0 + c) * 500 + uout] = hn;
      }
    }
  }
}

// ---------------- per-row log-softmax NLL ----------------
__device__ __forceinline__ float wave_max(float v) {
#pragma unroll
  for (int o = 32; o > 0; o >>= 1) v = fmaxf(v, __shfl_xor(v, o, 64));
  return v;
}
__device__ __forceinline__ float wave_sum(float v) {
#pragma unroll
  for (int o = 32; o > 0; o >>= 1) v += __shfl_xor(v, o, 64);
  return v;
}

__global__ __launch_bounds__(256) void loss_rows(
    const float* __restrict__ seq, const float* __restrict__ logits,
    const int* __restrict__ nseq, float* __restrict__ nll) {
  __shared__ float sm[8];
  const int r = blockIdx.x, tid = threadIdx.x;
  const int t = r >> 5, b = r & 31;
  const float* row = (t == 0) ? (seq + (long)b * VV)
                              : (logits + (long)((t - 1) * 32 + b) * VV);
  float m = -INFINITY;
  for (int c = tid; c < 1178; c += 256) {
    float4 v = *(const float4*)&row[c * 4];
    m = fmaxf(m, fmaxf(fmaxf(v.x, v.y), fmaxf(v.z, v.w)));
  }
  m = wave_max(m);
  const int wid = tid >> 6;
  if ((tid & 63) == 0) sm[wid] = m;
  __syncthreads();
  const float M4 = fmaxf(fmaxf(sm[0], sm[1]), fmaxf(sm[2], sm[3]));
  float s = 0.0f;
  for (int c = tid; c < 1178; c += 256) {
    float4 v = *(const float4*)&row[c * 4];
    s += expf(v.x - M4) + expf(v.y - M4) + expf(v.z - M4) + expf(v.w - M4);
  }
  s = wave_sum(s);
  if ((tid & 63) == 0) sm[4 + wid] = s;
  __syncthreads();
  if (tid == 0) {
    const float S = sm[4] + sm[5] + sm[6] + sm[7];
    const int tgt = nseq[(t << 5) + b];
    nll[r] = M4 + logf(S) - row[tgt];
  }
}

__global__ __launch_bounds__(256) void final_reduce(
    const float* __restrict__ nll, float* __restrict__ out) {
  __shared__ float sm[4];
  float s = 0.0f;
  for (int c = threadIdx.x; c < 8192; c += 256) s += nll[c];
  s = wave_sum(s);
  if ((threadIdx.x & 63) == 0) sm[threadIdx.x >> 6] = s;
  __syncthreads();
  if (threadIdx.x == 0) out[0] = (sm[0] + sm[1] + sm[2] + sm[3]) * (1.0f / 8192.0f);
}

// ---------------- launch ----------------
extern "C" void kernel_launch(void* const* d_in, const int* in_sizes, int n_in,
                              void* d_out, int out_size, void* d_ws, size_t ws_size,
                              hipStream_t stream) {
  (void)in_sizes; (void)n_in; (void)out_size; (void)ws_size;
  const float* seq  = (const float*)d_in[0];
  const int* nseq   = (const int*)d_in[1];
  const float* eWih = (const float*)d_in[2];
  const float* eWhh = (const float*)d_in[3];
  const float* ebih = (const float*)d_in[4];
  const float* ebhh = (const float*)d_in[5];
  const float* dWih = (const float*)d_in[6];
  const float* dWhh = (const float*)d_in[7];
  const float* dbih = (const float*)d_in[8];
  const float* dbhh = (const float*)d_in[9];
  const float* oW   = (const float*)d_in[10];
  const float* ob   = (const float*)d_in[11];

  float* wsf = (float*)d_ws;
  float* logits   = wsf;
  float* enc_preT = wsf;
  float* dec_preT = wsf + OFF_DECPRE;
  ull*   hring    = (ull*)(wsf + OFF_HR);
  float* dec_h    = wsf + OFF_DECH;
  float* nll      = wsf + OFF_NLL;

  // rings: {f32 0.0 | tag 0} everywhere; ring0 tag0 == initial h^0 (want=0)
  hipMemsetAsync(hring, 0, 3 * RING_SLOTS * sizeof(ull), stream);

  dim3 blk(256);
  // enc_preT[j][t*32+b] = eWih[j,:] . seq[(255-t)*32+b,:] + ebih[j]+ebhh[j]
  gemm_bf16<<<dim3(16, 64), blk, 0, stream>>>(eWih, VV, seq, VV, 1,
                                              1, ebih, ebhh,
                                              enc_preT, MPRE, FOURH, MPRE, VV);
  // dec_preT[j][t*32+b] = dWih[j,:] . seq[t*32+b,:] + dbih[j]+dbhh[j]
  gemm_bf16<<<dim3(16, 64), blk, 0, stream>>>(dWih, VV, seq, VV, 0,
                                              1, dbih, dbhh,
                                              dec_preT, MPRE, FOURH, MPRE, VV);
  // recurrence (encoder then decoder), writes dec_h
  lstm_rec<<<dim3(256), blk, 0, stream>>>(enc_preT, dec_preT, eWhh, dWhh,
                                          hring, dec_h);
  // logits = dec_h @ out_W^T + out_b  (overwrites preT buffers; dec_h disjoint)
  gemm_bf16<<<dim3(64, 37), blk, 0, stream>>>(dec_h, HH, oW, HH, 0,
                                              0, ob, nullptr,
                                              logits, VV, MPRE, VV, HH);
  // per-row NLL then deterministic reduce
  loss_rows<<<dim3(8192), blk, 0, stream>>>(seq, logits, nseq, nll);
  final_reduce<<<dim3(1), blk, 0, stream>>>(nll, (float*)d_out);
}

// Round 12
// 4476.355 us; speedup vs baseline: 6.3149x; 1.0144x over previous
//
#include <hip/hip_runtime.h>
#include <math.h>

typedef unsigned long long ull;
typedef __attribute__((ext_vector_type(8))) short s16x8;
typedef __attribute__((ext_vector_type(8))) unsigned short u16x8;
typedef __attribute__((ext_vector_type(4))) float f32x4;
typedef __attribute__((ext_vector_type(4))) unsigned int u32x4;

// Problem constants
#define TT 256
#define BB 32
#define VV 4712
#define HH 500
#define FOURH 2000
#define MPRE 8160          // 255*32

// ---------------- workspace layout (float offsets) ----------------
// logits   : 0 .. 38,449,920 (8160*4712)
//   enc_preT: 0 .. 16,320,000            overlaps logits
//   dec_preT: 16,320,000 .. 32,640,000   overlaps logits
//   hring   : 33,100,000 .. 33,198,304   (3 rings x 16384 x 8B tagged slots)
// dec_h    : 38,449,920 .. 42,529,920
// nll      : 42,561,920 .. 42,570,112
#define OFF_DECPRE 16320000
#define OFF_HR     33100000
#define OFF_DECH   38449920
#define OFF_NLL    42561920
#define RING_SLOTS 16384

__device__ __forceinline__ unsigned short f2b(float f) {
  unsigned int b = __float_as_uint(f);
  b = b + 0x7fffu + ((b >> 16) & 1u);   // round-to-nearest-even bf16
  return (unsigned short)(b >> 16);
}

// HW packed bf16 convert via inline asm (gfx950-verified instruction, T12/m214).
// dst low 16 = cvt(lo), high 16 = cvt(hi). NOT hip_bf16.h (NaN'd twice: r9,r11).
__device__ __forceinline__ unsigned cvtpk(float lo, float hi) {
  unsigned r;
  asm("v_cvt_pk_bf16_f32 %0, %1, %2" : "=v"(r) : "v"(lo), "v"(hi));
  return r;
}

// ---------------- bf16 MFMA GEMM: cvt_pk inline asm + dbuf pipeline -----------
// 128x128 tile, 4 waves, BK=32, LDS double-buffered. Per iter: issue next
// tile's global loads -> frag reads + MFMA on current buffer -> cvt_pk convert
// (16 insts/thread, vs ~110 for the f2b bit-twiddle = the VALU bottleneck) +
// store other buffer -> ONE barrier. Schedule byte-identical to r10 (verified).
__global__ __launch_bounds__(256) void gemm_bf16(
    const float* __restrict__ A, int lda,
    const float* __restrict__ W, int ldw, int rowmapW,
    int bias_mode, const float* __restrict__ b0, const float* __restrict__ b1,
    float* __restrict__ C, int ldc, int M, int N, int K) {
  __shared__ __align__(16) unsigned short As[2][128 * 40];
  __shared__ __align__(16) unsigned short Bs[2][128 * 40];

  const int tid = threadIdx.x;
  const int lane = tid & 63, wid = tid >> 6;
  const int wm = wid >> 1, wn = wid & 1;
  const int row16 = lane & 15, kq = lane >> 4;
  const int m0 = blockIdx.x * 128, n0 = blockIdx.y * 128;

  const int sr = tid >> 1;
  const int ks = (tid & 1) << 4;
  int am = m0 + sr; if (am >= M) am = M - 1;
  const float* arow = A + (long)am * lda;
  int nn = n0 + sr; if (nn >= N) nn = N - 1;
  int rn = nn;
  if (rowmapW) { int t = nn >> 5, b = nn & 31; rn = ((255 - t) << 5) + b; }
  const float* wrow = W + (long)rn * ldw;

  f32x4 acc[4][4];
#pragma unroll
  for (int i = 0; i < 4; ++i)
#pragma unroll
    for (int j = 0; j < 4; ++j) acc[i][j] = (f32x4){0.f, 0.f, 0.f, 0.f};

  float4 av[4], wv[4];

#define LOAD_TILE(kt_)                                                      \
  do {                                                                      \
    const int kb_ = (kt_) * 32 + ks;                                        \
    _Pragma("unroll")                                                       \
    for (int q = 0; q < 4; ++q) {                                           \
      const int k_ = kb_ + q * 4; /* K multiple of 4 in all our calls */    \
      if (k_ < K) {                                                         \
        av[q] = *(const float4*)(arow + k_);                                \
        wv[q] = *(const float4*)(wrow + k_);                                \
      } else {                                                              \
        av[q] = make_float4(0.f, 0.f, 0.f, 0.f);                            \
        wv[q] = make_float4(0.f, 0.f, 0.f, 0.f);                            \
      }                                                                     \
    }                                                                       \
  } while (0)

#define CVT_STORE(bq_)                                                      \
  do {                                                                      \
    const u32x4 qa0 = {cvtpk(av[0].x, av[0].y), cvtpk(av[0].z, av[0].w),    \
                       cvtpk(av[1].x, av[1].y), cvtpk(av[1].z, av[1].w)};   \
    const u32x4 qa1 = {cvtpk(av[2].x, av[2].y), cvtpk(av[2].z, av[2].w),    \
                       cvtpk(av[3].x, av[3].y), cvtpk(av[3].z, av[3].w)};   \
    const u32x4 qw0 = {cvtpk(wv[0].x, wv[0].y), cvtpk(wv[0].z, wv[0].w),    \
                       cvtpk(wv[1].x, wv[1].y), cvtpk(wv[1].z, wv[1].w)};   \
    const u32x4 qw1 = {cvtpk(wv[2].x, wv[2].y), cvtpk(wv[2].z, wv[2].w),    \
                       cvtpk(wv[3].x, wv[3].y), cvtpk(wv[3].z, wv[3].w)};   \
    *(u32x4*)&As[bq_][sr * 40 + ks + 0] = qa0;                              \
    *(u32x4*)&As[bq_][sr * 40 + ks + 8] = qa1;                              \
    *(u32x4*)&Bs[bq_][sr * 40 + ks + 0] = qw0;                              \
    *(u32x4*)&Bs[bq_][sr * 40 + ks + 8] = qw1;                              \
  } while (0)

  // prologue: tile 0 -> buffer 0
  LOAD_TILE(0);
  CVT_STORE(0);
  __syncthreads();

  const int KT = (K + 31) >> 5;
  for (int kt = 0; kt < KT; ++kt) {
    const int cur = kt & 1;
    const bool more = (kt + 1 < KT);
    if (more) LOAD_TILE(kt + 1);   // issue loads; complete under MFMA below

    s16x8 afrag[4], bfrag[4];
#pragma unroll
    for (int i = 0; i < 4; ++i)
      afrag[i] = *(const s16x8*)&As[cur][(wm * 64 + i * 16 + row16) * 40 + kq * 8];
#pragma unroll
    for (int j = 0; j < 4; ++j)
      bfrag[j] = *(const s16x8*)&Bs[cur][(wn * 64 + j * 16 + row16) * 40 + kq * 8];
#pragma unroll
    for (int i = 0; i < 4; ++i)
#pragma unroll
      for (int j = 0; j < 4; ++j)
        acc[i][j] = __builtin_amdgcn_mfma_f32_16x16x32_bf16(
            afrag[i], bfrag[j], acc[i][j], 0, 0, 0);

    if (more) {
      CVT_STORE(cur ^ 1);          // other buffer; prior reads of it done at
      __syncthreads();             // the previous barrier -> safe
    }
  }
#undef LOAD_TILE
#undef CVT_STORE

#pragma unroll
  for (int i = 0; i < 4; ++i) {
    const int rbase = m0 + wm * 64 + i * 16 + kq * 4;
#pragma unroll
    for (int r = 0; r < 4; ++r) {
      const int mrow = rbase + r;
      if (mrow < M) {
        const float rb = (bias_mode == 1) ? (b0[mrow] + b1[mrow]) : 0.0f;
        float* crow = C + (long)mrow * ldc;
#pragma unroll
        for (int j = 0; j < 4; ++j) {
          const int col = n0 + wn * 64 + j * 16 + row16;
          if (col < N) {
            float v = acc[i][j][r] + rb;
            if (bias_mode == 0 && b0) v += b0[col];
            crow[col] = v;
          }
        }
      }
    }
  }
}

// ---------------- persistent LSTM recurrence: tagged-ring exchange ------------
// (byte-identical logic to r8/r10 — kept frozen for clean attribution)
#define PITCH_H 544
__global__ __launch_bounds__(256) void lstm_rec(
    const float* __restrict__ enc_preT, const float* __restrict__ dec_preT,
    const float* __restrict__ enc_Whh, const float* __restrict__ dec_Whh,
    ull* __restrict__ hring, float* __restrict__ dec_h) {
  __shared__ __align__(16) unsigned short hb16[2][4 * PITCH_H];  // 8.5 KB

  const int tid = threadIdx.x;
  const int lane = tid & 63, w = tid >> 6;
  const int kq = lane >> 4;             // 0..3
  const int X = blockIdx.x & 31, Y = blockIdx.x >> 5;
  const int u0 = X * 16, b0 = Y * 4;

  const int arr = lane & 15;
  const int ag  = arr & 3;
  const int au  = u0 + w * 4 + (arr >> 2);
  const bool auok = (au < 500);

  const int c    = lane & 15;           // batch col (active if <4)
  const int uout = u0 + w * 4 + kq;
  const bool act = (c < 4) && (uout < 500);
  long preoff[4];
#pragma unroll
  for (int g = 0; g < 4; ++g)
    preoff[g] = (long)(g * 500 + (act ? uout : 0)) * MPRE + b0 + (act ? c : 0);

  if (tid < 352) {
    const int bq = tid / 176, rr = tid % 176;
    const int cc = rr / 44, k = 500 + rr % 44;
    hb16[bq][cc * PITCH_H + k] = 0;
  }
  __syncthreads();

  float creg = 0.0f;   // cell state (uout, b0+c) on active lanes

  const float* pres[2] = {enc_preT, dec_preT};
  const float* whhs[2] = {enc_Whh, dec_Whh};
  unsigned step = 0;   // global step 1..510 across both phases

  for (int ph = 0; ph < 2; ++ph) {
    const float* pre = pres[ph];
    const float* Whh = whhs[ph];

    s16x8 afrag[16];
    {
      const float* wrow = Whh + (long)(ag * 500 + (auok ? au : 0)) * 500;
#pragma unroll
      for (int ch = 0; ch < 16; ++ch) {
        const int k0 = ch * 32 + kq * 8;
        float4 v0 = make_float4(0.f, 0.f, 0.f, 0.f);
        float4 v1 = make_float4(0.f, 0.f, 0.f, 0.f);
        if (auok && k0 < 500)     v0 = *(const float4*)(wrow + k0);
        if (auok && k0 + 4 < 500) v1 = *(const float4*)(wrow + k0 + 4);
        const u16x8 p = {f2b(v0.x), f2b(v0.y), f2b(v0.z), f2b(v0.w),
                         f2b(v1.x), f2b(v1.y), f2b(v1.z), f2b(v1.w)};
        afrag[ch] = (s16x8)p;
      }
    }

    for (int t = 0; t < 255; ++t) {
      ++step;
      const unsigned want = step - 1;
      const int buf = step & 1;
      const ull* rring = hring + (ull)((step - 1) % 3) * RING_SLOTS;
      ull* wring = hring + (ull)(step % 3) * RING_SLOTS;

      float pv[4];
#pragma unroll
      for (int g = 0; g < 4; ++g) pv[g] = pre[preoff[g] + t * 32];

      unsigned pend = (tid < 208) ? 0xffu : 0x7fu;
      ull vals[8];
      while (pend) {
        unsigned np = pend;
#pragma unroll
        for (int j = 0; j < 8; ++j) {
          if (np & (1u << j)) {
            const int gi = tid + j * 256;
            const ull v = __hip_atomic_load(
                &rring[((gi >> 2) << 5) + b0 + (gi & 3)],
                __ATOMIC_RELAXED, __HIP_MEMORY_SCOPE_AGENT);
            if ((unsigned)(v >> 32) >= want) { vals[j] = v; np &= ~(1u << j); }
          }
        }
        pend = np;
        if (pend) __builtin_amdgcn_s_sleep(1);
      }
#pragma unroll
      for (int j = 0; j < 8; ++j) {
        const int gi = tid + j * 256;
        if (gi < 2000)
          hb16[buf][(gi & 3) * PITCH_H + (gi >> 2)] =
              f2b(__uint_as_float((unsigned)(vals[j] & 0xffffffffu)));
      }
      __syncthreads();

      f32x4 acc = (f32x4){0.f, 0.f, 0.f, 0.f};
      const unsigned short* hbase = &hb16[buf][(c & 3) * PITCH_H + kq * 8];
#pragma unroll
      for (int ch = 0; ch < 16; ++ch) {
        const s16x8 bfrag = *(const s16x8*)(hbase + ch * 32);
        acc = __builtin_amdgcn_mfma_f32_16x16x32_bf16(afrag[ch], bfrag, acc,
                                                      0, 0, 0);
      }

      if (act) {
        const float iv = acc[0] + pv[0];
        const float fv = acc[1] + pv[1];
        const float gv = acc[2] + pv[2];
        const float ov = acc[3] + pv[3];
        const float si = 1.0f / (1.0f + expf(-iv));
        const float sf = 1.0f / (1.0f + expf(-fv));
        const float so = 1.0f / (1.0f + expf(-ov));
        const float cn = sf * creg + si * tanhf(gv);
        const float hn = so * tanhf(cn);
        creg = cn;
        __hip_atomic_store(&wring[(uout << 5) + b0 + c],
                           ((ull)step << 32) | __float_as_uint(hn),
                           __ATOMIC_RELAXED, __HIP_MEMORY_SCOPE_AGENT);
        if (ph == 1)
          dec_h[(long)(t * 32 + b0 + c) * 500 + uout] = hn;
      }
    }
  }
}

// ---------------- per-row log-softmax NLL ----------------
__device__ __forceinline__ float wave_max(float v) {
#pragma unroll
  for (int o = 32; o > 0; o >>= 1) v = fmaxf(v, __shfl_xor(v, o, 64));
  return v;
}
__device__ __forceinline__ float wave_sum(float v) {
#pragma unroll
  for (int o = 32; o > 0; o >>= 1) v += __shfl_xor(v, o, 64);
  return v;
}

__global__ __launch_bounds__(256) void loss_rows(
    const float* __restrict__ seq, const float* __restrict__ logits,
    const int* __restrict__ nseq, float* __restrict__ nll) {
  __shared__ float sm[8];
  const int r = blockIdx.x, tid = threadIdx.x;
  const int t = r >> 5, b = r & 31;
  const float* row = (t == 0) ? (seq + (long)b * VV)
                              : (logits + (long)((t - 1) * 32 + b) * VV);
  float m = -INFINITY;
  for (int c = tid; c < 1178; c += 256) {
    float4 v = *(const float4*)&row[c * 4];
    m = fmaxf(m, fmaxf(fmaxf(v.x, v.y), fmaxf(v.z, v.w)));
  }
  m = wave_max(m);
  const int wid = tid >> 6;
  if ((tid & 63) == 0) sm[wid] = m;
  __syncthreads();
  const float M4 = fmaxf(fmaxf(sm[0], sm[1]), fmaxf(sm[2], sm[3]));
  float s = 0.0f;
  for (int c = tid; c < 1178; c += 256) {
    float4 v = *(const float4*)&row[c * 4];
    s += expf(v.x - M4) + expf(v.y - M4) + expf(v.z - M4) + expf(v.w - M4);
  }
  s = wave_sum(s);
  if ((tid & 63) == 0) sm[4 + wid] = s;
  __syncthreads();
  if (tid == 0) {
    const float S = sm[4] + sm[5] + sm[6] + sm[7];
    const int tgt = nseq[(t << 5) + b];
    nll[r] = M4 + logf(S) - row[tgt];
  }
}

__global__ __launch_bounds__(256) void final_reduce(
    const float* __restrict__ nll, float* __restrict__ out) {
  __shared__ float sm[4];
  float s = 0.0f;
  for (int c = threadIdx.x; c < 8192; c += 256) s += nll[c];
  s = wave_sum(s);
  if ((threadIdx.x & 63) == 0) sm[threadIdx.x >> 6] = s;
  __syncthreads();
  if (threadIdx.x == 0) out[0] = (sm[0] + sm[1] + sm[2] + sm[3]) * (1.0f / 8192.0f);
}

// ---------------- launch ----------------
extern "C" void kernel_launch(void* const* d_in, const int* in_sizes, int n_in,
                              void* d_out, int out_size, void* d_ws, size_t ws_size,
                              hipStream_t stream) {
  (void)in_sizes; (void)n_in; (void)out_size; (void)ws_size;
  const float* seq  = (const float*)d_in[0];
  const int* nseq   = (const int*)d_in[1];
  const float* eWih = (const float*)d_in[2];
  const float* eWhh = (const float*)d_in[3];
  const float* ebih = (const float*)d_in[4];
  const float* ebhh = (const float*)d_in[5];
  const float* dWih = (const float*)d_in[6];
  const float* dWhh = (const float*)d_in[7];
  const float* dbih = (const float*)d_in[8];
  const float* dbhh = (const float*)d_in[9];
  const float* oW   = (const float*)d_in[10];
  const float* ob   = (const float*)d_in[11];

  float* wsf = (float*)d_ws;
  float* logits   = wsf;
  float* enc_preT = wsf;
  float* dec_preT = wsf + OFF_DECPRE;
  ull*   hring    = (ull*)(wsf + OFF_HR);
  float* dec_h    = wsf + OFF_DECH;
  float* nll      = wsf + OFF_NLL;

  // rings: {f32 0.0 | tag 0} everywhere; ring0 tag0 == initial h^0 (want=0)
  hipMemsetAsync(hring, 0, 3 * RING_SLOTS * sizeof(ull), stream);

  dim3 blk(256);
  // enc_preT[j][t*32+b] = eWih[j,:] . seq[(255-t)*32+b,:] + ebih[j]+ebhh[j]
  gemm_bf16<<<dim3(16, 64), blk, 0, stream>>>(eWih, VV, seq, VV, 1,
                                              1, ebih, ebhh,
                                              enc_preT, MPRE, FOURH, MPRE, VV);
  // dec_preT[j][t*32+b] = dWih[j,:] . seq[t*32+b,:] + dbih[j]+dbhh[j]
  gemm_bf16<<<dim3(16, 64), blk, 0, stream>>>(dWih, VV, seq, VV, 0,
                                              1, dbih, dbhh,
                                              dec_preT, MPRE, FOURH, MPRE, VV);
  // recurrence (encoder then decoder), writes dec_h
  lstm_rec<<<dim3(256), blk, 0, stream>>>(enc_preT, dec_preT, eWhh, dWhh,
                                          hring, dec_h);
  // logits = dec_h @ out_W^T + out_b  (overwrites preT buffers; dec_h disjoint)
  gemm_bf16<<<dim3(64, 37), blk, 0, stream>>>(dec_h, HH, oW, HH, 0,
                                              0, ob, nullptr,
                                              logits, VV, MPRE, VV, HH);
  // per-row NLL then deterministic reduce
  loss_rows<<<dim3(8192), blk, 0, stream>>>(seq, logits, nseq, nll);
  final_reduce<<<dim3(1), blk, 0, stream>>>(nll, (float*)d_out);
}

// Round 13
// 3567.334 us; speedup vs baseline: 7.9240x; 1.2548x over previous
//
#include <hip/hip_runtime.h>
#include <math.h>

typedef unsigned long long ull;
typedef __attribute__((ext_vector_type(8))) short s16x8;
typedef __attribute__((ext_vector_type(8))) unsigned short u16x8;
typedef __attribute__((ext_vector_type(4))) float f32x4;
typedef __attribute__((ext_vector_type(4))) unsigned int u32x4;

// Problem constants
#define TT 256
#define BB 32
#define VV 4712
#define HH 500
#define FOURH 2000
#define MPRE 8160          // 255*32

// ---------------- workspace layout (float offsets) ----------------
#define OFF_DECPRE 16320000
#define OFF_HR     33100000
#define OFF_DECH   38449920
#define OFF_NLL    42561920
#define RING_SLOTS 16384

__device__ __forceinline__ unsigned short f2b(float f) {
  unsigned int b = __float_as_uint(f);
  b = b + 0x7fffu + ((b >> 16) & 1u);   // round-to-nearest-even bf16
  return (unsigned short)(b >> 16);
}

// HW packed bf16 convert via inline asm (verified r12). NOT hip_bf16.h (r9/r11 NaN).
__device__ __forceinline__ unsigned cvtpk(float lo, float hi) {
  unsigned r;
  asm("v_cvt_pk_bf16_f32 %0, %1, %2" : "=v"(r) : "v"(lo), "v"(hi));
  return r;
}

// ---------------- bf16 MFMA GEMM, 256x256 tile ("traffic" version) ------------
// 512 threads = 8 waves (2x4), wave tile 128x64 (acc[8][4]). BK=32, LDS dbuf
// (80 KB), cvt_pk conversion + reg prefetch (both verified r12). Halves operand
// traffic vs 128^2: (N/256)|A| + (M/256)|W|. swz=1 (pre-GEMMs, mtiles==8):
// mt = bid&7 so each XCD's 32 blocks (bid%8 == XCD under round-robin dispatch)
// share one A-panel -> panel lives in that XCD's L2; W slabs hit L3 after the
// first XCD. Mapping is a locality heuristic only — correctness independent.
__global__ __launch_bounds__(512) void gemm_bf16_256(
    const float* __restrict__ A, int lda,
    const float* __restrict__ W, int ldw, int rowmapW,
    int bias_mode, const float* __restrict__ b0, const float* __restrict__ b1,
    float* __restrict__ C, int ldc, int M, int N, int K,
    int ntiles, int swz) {
  __shared__ __align__(16) unsigned short As[2][256 * 40];
  __shared__ __align__(16) unsigned short Bs[2][256 * 40];

  const int tid = threadIdx.x;
  const int lane = tid & 63, wid = tid >> 6;
  const int wm = wid >> 2, wn = wid & 3;        // 2x4 wave grid, wave 128x64
  const int row16 = lane & 15, kq = lane >> 4;
  int mt, nt;
  if (swz) { mt = blockIdx.x & 7; nt = blockIdx.x >> 3; }
  else     { nt = blockIdx.x % ntiles; mt = blockIdx.x / ntiles; }
  const int m0 = mt * 256, n0 = nt * 256;

  const int sr = tid >> 1;          // 0..255 staging row
  const int ks = (tid & 1) << 4;
  int am = m0 + sr; if (am >= M) am = M - 1;
  const float* arow = A + (long)am * lda;
  int nn = n0 + sr; if (nn >= N) nn = N - 1;
  int rn = nn;
  if (rowmapW) { int t = nn >> 5, b = nn & 31; rn = ((255 - t) << 5) + b; }
  const float* wrow = W + (long)rn * ldw;

  f32x4 acc[8][4];
#pragma unroll
  for (int i = 0; i < 8; ++i)
#pragma unroll
    for (int j = 0; j < 4; ++j) acc[i][j] = (f32x4){0.f, 0.f, 0.f, 0.f};

  float4 av[4], wv[4];

#define LOAD_TILE(kt_)                                                      \
  do {                                                                      \
    const int kb_ = (kt_) * 32 + ks;                                        \
    _Pragma("unroll")                                                       \
    for (int q = 0; q < 4; ++q) {                                           \
      const int k_ = kb_ + q * 4; /* K multiple of 4 in all our calls */    \
      if (k_ < K) {                                                         \
        av[q] = *(const float4*)(arow + k_);                                \
        wv[q] = *(const float4*)(wrow + k_);                                \
      } else {                                                              \
        av[q] = make_float4(0.f, 0.f, 0.f, 0.f);                            \
        wv[q] = make_float4(0.f, 0.f, 0.f, 0.f);                            \
      }                                                                     \
    }                                                                       \
  } while (0)

#define CVT_STORE(bq_)                                                      \
  do {                                                                      \
    const u32x4 qa0 = {cvtpk(av[0].x, av[0].y), cvtpk(av[0].z, av[0].w),    \
                       cvtpk(av[1].x, av[1].y), cvtpk(av[1].z, av[1].w)};   \
    const u32x4 qa1 = {cvtpk(av[2].x, av[2].y), cvtpk(av[2].z, av[2].w),    \
                       cvtpk(av[3].x, av[3].y), cvtpk(av[3].z, av[3].w)};   \
    const u32x4 qw0 = {cvtpk(wv[0].x, wv[0].y), cvtpk(wv[0].z, wv[0].w),    \
                       cvtpk(wv[1].x, wv[1].y), cvtpk(wv[1].z, wv[1].w)};   \
    const u32x4 qw1 = {cvtpk(wv[2].x, wv[2].y), cvtpk(wv[2].z, wv[2].w),    \
                       cvtpk(wv[3].x, wv[3].y), cvtpk(wv[3].z, wv[3].w)};   \
    *(u32x4*)&As[bq_][sr * 40 + ks + 0] = qa0;                              \
    *(u32x4*)&As[bq_][sr * 40 + ks + 8] = qa1;                              \
    *(u32x4*)&Bs[bq_][sr * 40 + ks + 0] = qw0;                              \
    *(u32x4*)&Bs[bq_][sr * 40 + ks + 8] = qw1;                              \
  } while (0)

  // prologue: tile 0 -> buffer 0
  LOAD_TILE(0);
  CVT_STORE(0);
  __syncthreads();

  const int KT = (K + 31) >> 5;
  for (int kt = 0; kt < KT; ++kt) {
    const int cur = kt & 1;
    const bool more = (kt + 1 < KT);
    if (more) LOAD_TILE(kt + 1);   // issue loads; complete under MFMA below

    s16x8 afrag[8], bfrag[4];
#pragma unroll
    for (int i = 0; i < 8; ++i)
      afrag[i] = *(const s16x8*)&As[cur][(wm * 128 + i * 16 + row16) * 40 + kq * 8];
#pragma unroll
    for (int j = 0; j < 4; ++j)
      bfrag[j] = *(const s16x8*)&Bs[cur][(wn * 64 + j * 16 + row16) * 40 + kq * 8];
#pragma unroll
    for (int i = 0; i < 8; ++i)
#pragma unroll
      for (int j = 0; j < 4; ++j)
        acc[i][j] = __builtin_amdgcn_mfma_f32_16x16x32_bf16(
            afrag[i], bfrag[j], acc[i][j], 0, 0, 0);

    if (more) {
      CVT_STORE(cur ^ 1);          // other buffer; prior reads done at the
      __syncthreads();             // previous barrier -> safe
    }
  }
#undef LOAD_TILE
#undef CVT_STORE

#pragma unroll
  for (int i = 0; i < 8; ++i) {
    const int rbase = m0 + wm * 128 + i * 16 + kq * 4;
#pragma unroll
    for (int r = 0; r < 4; ++r) {
      const int mrow = rbase + r;
      if (mrow < M) {
        const float rb = (bias_mode == 1) ? (b0[mrow] + b1[mrow]) : 0.0f;
        float* crow = C + (long)mrow * ldc;
#pragma unroll
        for (int j = 0; j < 4; ++j) {
          const int col = n0 + wn * 64 + j * 16 + row16;
          if (col < N) {
            float v = acc[i][j][r] + rb;
            if (bias_mode == 0 && b0) v += b0[col];
            crow[col] = v;
          }
        }
      }
    }
  }
}

// ---------------- persistent LSTM recurrence: tagged-ring exchange ------------
// (byte-identical logic to r8/r10/r12 — kept frozen for clean attribution)
#define PITCH_H 544
__global__ __launch_bounds__(256) void lstm_rec(
    const float* __restrict__ enc_preT, const float* __restrict__ dec_preT,
    const float* __restrict__ enc_Whh, const float* __restrict__ dec_Whh,
    ull* __restrict__ hring, float* __restrict__ dec_h) {
  __shared__ __align__(16) unsigned short hb16[2][4 * PITCH_H];  // 8.5 KB

  const int tid = threadIdx.x;
  const int lane = tid & 63, w = tid >> 6;
  const int kq = lane >> 4;             // 0..3
  const int X = blockIdx.x & 31, Y = blockIdx.x >> 5;
  const int u0 = X * 16, b0 = Y * 4;

  const int arr = lane & 15;
  const int ag  = arr & 3;
  const int au  = u0 + w * 4 + (arr >> 2);
  const bool auok = (au < 500);

  const int c    = lane & 15;           // batch col (active if <4)
  const int uout = u0 + w * 4 + kq;
  const bool act = (c < 4) && (uout < 500);
  long preoff[4];
#pragma unroll
  for (int g = 0; g < 4; ++g)
    preoff[g] = (long)(g * 500 + (act ? uout : 0)) * MPRE + b0 + (act ? c : 0);

  if (tid < 352) {
    const int bq = tid / 176, rr = tid % 176;
    const int cc = rr / 44, k = 500 + rr % 44;
    hb16[bq][cc * PITCH_H + k] = 0;
  }
  __syncthreads();

  float creg = 0.0f;   // cell state (uout, b0+c) on active lanes

  const float* pres[2] = {enc_preT, dec_preT};
  const float* whhs[2] = {enc_Whh, dec_Whh};
  unsigned step = 0;   // global step 1..510 across both phases

  for (int ph = 0; ph < 2; ++ph) {
    const float* pre = pres[ph];
    const float* Whh = whhs[ph];

    s16x8 afrag[16];
    {
      const float* wrow = Whh + (long)(ag * 500 + (auok ? au : 0)) * 500;
#pragma unroll
      for (int ch = 0; ch < 16; ++ch) {
        const int k0 = ch * 32 + kq * 8;
        float4 v0 = make_float4(0.f, 0.f, 0.f, 0.f);
        float4 v1 = make_float4(0.f, 0.f, 0.f, 0.f);
        if (auok && k0 < 500)     v0 = *(const float4*)(wrow + k0);
        if (auok && k0 + 4 < 500) v1 = *(const float4*)(wrow + k0 + 4);
        const u16x8 p = {f2b(v0.x), f2b(v0.y), f2b(v0.z), f2b(v0.w),
                         f2b(v1.x), f2b(v1.y), f2b(v1.z), f2b(v1.w)};
        afrag[ch] = (s16x8)p;
      }
    }

    for (int t = 0; t < 255; ++t) {
      ++step;
      const unsigned want = step - 1;
      const int buf = step & 1;
      const ull* rring = hring + (ull)((step - 1) % 3) * RING_SLOTS;
      ull* wring = hring + (ull)(step % 3) * RING_SLOTS;

      float pv[4];
#pragma unroll
      for (int g = 0; g < 4; ++g) pv[g] = pre[preoff[g] + t * 32];

      unsigned pend = (tid < 208) ? 0xffu : 0x7fu;
      ull vals[8];
      while (pend) {
        unsigned np = pend;
#pragma unroll
        for (int j = 0; j < 8; ++j) {
          if (np & (1u << j)) {
            const int gi = tid + j * 256;
            const ull v = __hip_atomic_load(
                &rring[((gi >> 2) << 5) + b0 + (gi & 3)],
                __ATOMIC_RELAXED, __HIP_MEMORY_SCOPE_AGENT);
            if ((unsigned)(v >> 32) >= want) { vals[j] = v; np &= ~(1u << j); }
          }
        }
        pend = np;
        if (pend) __builtin_amdgcn_s_sleep(1);
      }
#pragma unroll
      for (int j = 0; j < 8; ++j) {
        const int gi = tid + j * 256;
        if (gi < 2000)
          hb16[buf][(gi & 3) * PITCH_H + (gi >> 2)] =
              f2b(__uint_as_float((unsigned)(vals[j] & 0xffffffffu)));
      }
      __syncthreads();

      f32x4 acc = (f32x4){0.f, 0.f, 0.f, 0.f};
      const unsigned short* hbase = &hb16[buf][(c & 3) * PITCH_H + kq * 8];
#pragma unroll
      for (int ch = 0; ch < 16; ++ch) {
        const s16x8 bfrag = *(const s16x8*)(hbase + ch * 32);
        acc = __builtin_amdgcn_mfma_f32_16x16x32_bf16(afrag[ch], bfrag, acc,
                                                      0, 0, 0);
      }

      if (act) {
        const float iv = acc[0] + pv[0];
        const float fv = acc[1] + pv[1];
        const float gv = acc[2] + pv[2];
        const float ov = acc[3] + pv[3];
        const float si = 1.0f / (1.0f + expf(-iv));
        const float sf = 1.0f / (1.0f + expf(-fv));
        const float so = 1.0f / (1.0f + expf(-ov));
        const float cn = sf * creg + si * tanhf(gv);
        const float hn = so * tanhf(cn);
        creg = cn;
        __hip_atomic_store(&wring[(uout << 5) + b0 + c],
                           ((ull)step << 32) | __float_as_uint(hn),
                           __ATOMIC_RELAXED, __HIP_MEMORY_SCOPE_AGENT);
        if (ph == 1)
          dec_h[(long)(t * 32 + b0 + c) * 500 + uout] = hn;
      }
    }
  }
}

// ---------------- per-row log-softmax NLL ----------------
__device__ __forceinline__ float wave_max(float v) {
#pragma unroll
  for (int o = 32; o > 0; o >>= 1) v = fmaxf(v, __shfl_xor(v, o, 64));
  return v;
}
__device__ __forceinline__ float wave_sum(float v) {
#pragma unroll
  for (int o = 32; o > 0; o >>= 1) v += __shfl_xor(v, o, 64);
  return v;
}

__global__ __launch_bounds__(256) void loss_rows(
    const float* __restrict__ seq, const float* __restrict__ logits,
    const int* __restrict__ nseq, float* __restrict__ nll) {
  __shared__ float sm[8];
  const int r = blockIdx.x, tid = threadIdx.x;
  const int t = r >> 5, b = r & 31;
  const float* row = (t == 0) ? (seq + (long)b * VV)
                              : (logits + (long)((t - 1) * 32 + b) * VV);
  float m = -INFINITY;
  for (int c = tid; c < 1178; c += 256) {
    float4 v = *(const float4*)&row[c * 4];
    m = fmaxf(m, fmaxf(fmaxf(v.x, v.y), fmaxf(v.z, v.w)));
  }
  m = wave_max(m);
  const int wid = tid >> 6;
  if ((tid & 63) == 0) sm[wid] = m;
  __syncthreads();
  const float M4 = fmaxf(fmaxf(sm[0], sm[1]), fmaxf(sm[2], sm[3]));
  float s = 0.0f;
  for (int c = tid; c < 1178; c += 256) {
    float4 v = *(const float4*)&row[c * 4];
    s += expf(v.x - M4) + expf(v.y - M4) + expf(v.z - M4) + expf(v.w - M4);
  }
  s = wave_sum(s);
  if ((tid & 63) == 0) sm[4 + wid] = s;
  __syncthreads();
  if (tid == 0) {
    const float S = sm[4] + sm[5] + sm[6] + sm[7];
    const int tgt = nseq[(t << 5) + b];
    nll[r] = M4 + logf(S) - row[tgt];
  }
}

__global__ __launch_bounds__(256) void final_reduce(
    const float* __restrict__ nll, float* __restrict__ out) {
  __shared__ float sm[4];
  float s = 0.0f;
  for (int c = threadIdx.x; c < 8192; c += 256) s += nll[c];
  s = wave_sum(s);
  if ((threadIdx.x & 63) == 0) sm[threadIdx.x >> 6] = s;
  __syncthreads();
  if (threadIdx.x == 0) out[0] = (sm[0] + sm[1] + sm[2] + sm[3]) * (1.0f / 8192.0f);
}

// ---------------- launch ----------------
extern "C" void kernel_launch(void* const* d_in, const int* in_sizes, int n_in,
                              void* d_out, int out_size, void* d_ws, size_t ws_size,
                              hipStream_t stream) {
  (void)in_sizes; (void)n_in; (void)out_size; (void)ws_size;
  const float* seq  = (const float*)d_in[0];
  const int* nseq   = (const int*)d_in[1];
  const float* eWih = (const float*)d_in[2];
  const float* eWhh = (const float*)d_in[3];
  const float* ebih = (const float*)d_in[4];
  const float* ebhh = (const float*)d_in[5];
  const float* dWih = (const float*)d_in[6];
  const float* dWhh = (const float*)d_in[7];
  const float* dbih = (const float*)d_in[8];
  const float* dbhh = (const float*)d_in[9];
  const float* oW   = (const float*)d_in[10];
  const float* ob   = (const float*)d_in[11];

  float* wsf = (float*)d_ws;
  float* logits   = wsf;
  float* enc_preT = wsf;
  float* dec_preT = wsf + OFF_DECPRE;
  ull*   hring    = (ull*)(wsf + OFF_HR);
  float* dec_h    = wsf + OFF_DECH;
  float* nll      = wsf + OFF_NLL;

  // rings: {f32 0.0 | tag 0} everywhere; ring0 tag0 == initial h^0 (want=0)
  hipMemsetAsync(hring, 0, 3 * RING_SLOTS * sizeof(ull), stream);

  // enc_preT[j][t*32+b] = eWih[j,:] . seq[(255-t)*32+b,:] + ebih[j]+ebhh[j]
  // grid 256 = 8 mtiles x 32 ntiles, swz=1 (mt = bid&7, XCD-affine A panels)
  gemm_bf16_256<<<dim3(256), dim3(512), 0, stream>>>(
      eWih, VV, seq, VV, 1, 1, ebih, ebhh,
      enc_preT, MPRE, FOURH, MPRE, VV, 32, 1);
  // dec_preT[j][t*32+b] = dWih[j,:] . seq[t*32+b,:] + dbih[j]+dbhh[j]
  gemm_bf16_256<<<dim3(256), dim3(512), 0, stream>>>(
      dWih, VV, seq, VV, 0, 1, dbih, dbhh,
      dec_preT, MPRE, FOURH, MPRE, VV, 32, 1);
  // recurrence (encoder then decoder), writes dec_h
  lstm_rec<<<dim3(256), dim3(256), 0, stream>>>(enc_preT, dec_preT, eWhh, dWhh,
                                                hring, dec_h);
  // logits = dec_h @ out_W^T + out_b  (32 mtiles x 19 ntiles = 608 blocks)
  gemm_bf16_256<<<dim3(608), dim3(512), 0, stream>>>(
      dec_h, HH, oW, HH, 0, 0, ob, nullptr,
      logits, VV, MPRE, VV, HH, 19, 0);
  // per-row NLL then deterministic reduce
  loss_rows<<<dim3(8192), dim3(256), 0, stream>>>(seq, logits, nseq, nll);
  final_reduce<<<dim3(1), dim3(256), 0, stream>>>(nll, (float*)d_out);
}

// Round 14
// 3231.382 us; speedup vs baseline: 8.7478x; 1.1040x over previous
//
#include <hip/hip_runtime.h>
#include <math.h>

typedef unsigned long long ull;
typedef __attribute__((ext_vector_type(8))) short s16x8;
typedef __attribute__((ext_vector_type(8))) unsigned short u16x8;
typedef __attribute__((ext_vector_type(4))) float f32x4;
typedef __attribute__((ext_vector_type(4))) unsigned int u32x4;

// Problem constants
#define TT 256
#define BB 32
#define VV 4712
#define HH 500
#define FOURH 2000
#define MPRE 8160          // 255*32

// ---------------- workspace layout (float offsets) ----------------
#define OFF_DECPRE 16320000
#define OFF_HR     33100000
#define OFF_DECH   38449920
#define OFF_NLL    42561920
#define RING_SLOTS 16384   // per ring: 8 groups x 2048 slots (2000 used)

__device__ __forceinline__ unsigned short f2b(float f) {
  unsigned int b = __float_as_uint(f);
  b = b + 0x7fffu + ((b >> 16) & 1u);   // round-to-nearest-even bf16
  return (unsigned short)(b >> 16);
}

// HW packed bf16 convert via inline asm (verified r12). NOT hip_bf16.h (r9/r11 NaN).
__device__ __forceinline__ unsigned cvtpk(float lo, float hi) {
  unsigned r;
  asm("v_cvt_pk_bf16_f32 %0, %1, %2" : "=v"(r) : "v"(lo), "v"(hi));
  return r;
}

// fast transcendentals (native v_exp; inf-safe forms; deterministic)
__device__ __forceinline__ float fsig(float x) {
  return 1.0f / (1.0f + __expf(-x));
}
__device__ __forceinline__ float ftanh(float x) {
  return 1.0f - 2.0f / (__expf(2.0f * x) + 1.0f);   // x=+inf -> 1, -inf -> -1
}

// ---------------- bf16 MFMA GEMM, 256x256 tile (unchanged from r13) -----------
__global__ __launch_bounds__(512) void gemm_bf16_256(
    const float* __restrict__ A, int lda,
    const float* __restrict__ W, int ldw, int rowmapW,
    int bias_mode, const float* __restrict__ b0, const float* __restrict__ b1,
    float* __restrict__ C, int ldc, int M, int N, int K,
    int ntiles, int swz) {
  __shared__ __align__(16) unsigned short As[2][256 * 40];
  __shared__ __align__(16) unsigned short Bs[2][256 * 40];

  const int tid = threadIdx.x;
  const int lane = tid & 63, wid = tid >> 6;
  const int wm = wid >> 2, wn = wid & 3;        // 2x4 wave grid, wave 128x64
  const int row16 = lane & 15, kq = lane >> 4;
  int mt, nt;
  if (swz) { mt = blockIdx.x & 7; nt = blockIdx.x >> 3; }
  else     { nt = blockIdx.x % ntiles; mt = blockIdx.x / ntiles; }
  const int m0 = mt * 256, n0 = nt * 256;

  const int sr = tid >> 1;          // 0..255 staging row
  const int ks = (tid & 1) << 4;
  int am = m0 + sr; if (am >= M) am = M - 1;
  const float* arow = A + (long)am * lda;
  int nn = n0 + sr; if (nn >= N) nn = N - 1;
  int rn = nn;
  if (rowmapW) { int t = nn >> 5, b = nn & 31; rn = ((255 - t) << 5) + b; }
  const float* wrow = W + (long)rn * ldw;

  f32x4 acc[8][4];
#pragma unroll
  for (int i = 0; i < 8; ++i)
#pragma unroll
    for (int j = 0; j < 4; ++j) acc[i][j] = (f32x4){0.f, 0.f, 0.f, 0.f};

  float4 av[4], wv[4];

#define LOAD_TILE(kt_)                                                      \
  do {                                                                      \
    const int kb_ = (kt_) * 32 + ks;                                        \
    _Pragma("unroll")                                                       \
    for (int q = 0; q < 4; ++q) {                                           \
      const int k_ = kb_ + q * 4; /* K multiple of 4 in all our calls */    \
      if (k_ < K) {                                                         \
        av[q] = *(const float4*)(arow + k_);                                \
        wv[q] = *(const float4*)(wrow + k_);                                \
      } else {                                                              \
        av[q] = make_float4(0.f, 0.f, 0.f, 0.f);                            \
        wv[q] = make_float4(0.f, 0.f, 0.f, 0.f);                            \
      }                                                                     \
    }                                                                       \
  } while (0)

#define CVT_STORE(bq_)                                                      \
  do {                                                                      \
    const u32x4 qa0 = {cvtpk(av[0].x, av[0].y), cvtpk(av[0].z, av[0].w),    \
                       cvtpk(av[1].x, av[1].y), cvtpk(av[1].z, av[1].w)};   \
    const u32x4 qa1 = {cvtpk(av[2].x, av[2].y), cvtpk(av[2].z, av[2].w),    \
                       cvtpk(av[3].x, av[3].y), cvtpk(av[3].z, av[3].w)};   \
    const u32x4 qw0 = {cvtpk(wv[0].x, wv[0].y), cvtpk(wv[0].z, wv[0].w),    \
                       cvtpk(wv[1].x, wv[1].y), cvtpk(wv[1].z, wv[1].w)};   \
    const u32x4 qw1 = {cvtpk(wv[2].x, wv[2].y), cvtpk(wv[2].z, wv[2].w),    \
                       cvtpk(wv[3].x, wv[3].y), cvtpk(wv[3].z, wv[3].w)};   \
    *(u32x4*)&As[bq_][sr * 40 + ks + 0] = qa0;                              \
    *(u32x4*)&As[bq_][sr * 40 + ks + 8] = qa1;                              \
    *(u32x4*)&Bs[bq_][sr * 40 + ks + 0] = qw0;                              \
    *(u32x4*)&Bs[bq_][sr * 40 + ks + 8] = qw1;                              \
  } while (0)

  // prologue: tile 0 -> buffer 0
  LOAD_TILE(0);
  CVT_STORE(0);
  __syncthreads();

  const int KT = (K + 31) >> 5;
  for (int kt = 0; kt < KT; ++kt) {
    const int cur = kt & 1;
    const bool more = (kt + 1 < KT);
    if (more) LOAD_TILE(kt + 1);   // issue loads; complete under MFMA below

    s16x8 afrag[8], bfrag[4];
#pragma unroll
    for (int i = 0; i < 8; ++i)
      afrag[i] = *(const s16x8*)&As[cur][(wm * 128 + i * 16 + row16) * 40 + kq * 8];
#pragma unroll
    for (int j = 0; j < 4; ++j)
      bfrag[j] = *(const s16x8*)&Bs[cur][(wn * 64 + j * 16 + row16) * 40 + kq * 8];
#pragma unroll
    for (int i = 0; i < 8; ++i)
#pragma unroll
      for (int j = 0; j < 4; ++j)
        acc[i][j] = __builtin_amdgcn_mfma_f32_16x16x32_bf16(
            afrag[i], bfrag[j], acc[i][j], 0, 0, 0);

    if (more) {
      CVT_STORE(cur ^ 1);          // other buffer; prior reads done at the
      __syncthreads();             // previous barrier -> safe
    }
  }
#undef LOAD_TILE
#undef CVT_STORE

#pragma unroll
  for (int i = 0; i < 8; ++i) {
    const int rbase = m0 + wm * 128 + i * 16 + kq * 4;
#pragma unroll
    for (int r = 0; r < 4; ++r) {
      const int mrow = rbase + r;
      if (mrow < M) {
        const float rb = (bias_mode == 1) ? (b0[mrow] + b1[mrow]) : 0.0f;
        float* crow = C + (long)mrow * ldc;
#pragma unroll
        for (int j = 0; j < 4; ++j) {
          const int col = n0 + wn * 64 + j * 16 + row16;
          if (col < N) {
            float v = acc[i][j][r] + rb;
            if (bias_mode == 0 && b0) v += b0[col];
            crow[col] = v;
          }
        }
      }
    }
  }
}

// ---------------- persistent LSTM recurrence: tagged-ring, coalesced layout ---
// Ring layout v2: ring[step%3][Y][u*4+c] — per-group slots are CONTIGUOUS.
// Consumer gather is coalesced (lane loads slot gbase+tid+j*256: 512B/wave
// runs); producer's 64 stores form one 512B run. 4x fewer IC transactions per
// poll round than r8's [u][32] layout. LDS write happens per-arrival (inside
// the poll loop), so stragglers don't delay completed slots. Gate nonlinearity
// uses native-exp forms (producer tail shortens).
#define PITCH_H 544
__global__ __launch_bounds__(256) void lstm_rec(
    const float* __restrict__ enc_preT, const float* __restrict__ dec_preT,
    const float* __restrict__ enc_Whh, const float* __restrict__ dec_Whh,
    ull* __restrict__ hring, float* __restrict__ dec_h) {
  __shared__ __align__(16) unsigned short hb16[2][4 * PITCH_H];  // 8.5 KB

  const int tid = threadIdx.x;
  const int lane = tid & 63, w = tid >> 6;
  const int kq = lane >> 4;             // 0..3
  const int X = blockIdx.x & 31, Y = blockIdx.x >> 5;
  const int u0 = X * 16, b0 = Y * 4;
  const int gbase = Y * 2048;           // group's slot base within a ring

  const int arr = lane & 15;
  const int ag  = arr & 3;
  const int au  = u0 + w * 4 + (arr >> 2);
  const bool auok = (au < 500);

  const int c    = lane & 15;           // batch col (active if <4)
  const int uout = u0 + w * 4 + kq;
  const bool act = (c < 4) && (uout < 500);
  long preoff[4];
#pragma unroll
  for (int g = 0; g < 4; ++g)
    preoff[g] = (long)(g * 500 + (act ? uout : 0)) * MPRE + b0 + (act ? c : 0);

  if (tid < 352) {
    const int bq = tid / 176, rr = tid % 176;
    const int cc = rr / 44, k = 500 + rr % 44;
    hb16[bq][cc * PITCH_H + k] = 0;
  }
  __syncthreads();

  float creg = 0.0f;   // cell state (uout, b0+c) on active lanes

  const float* pres[2] = {enc_preT, dec_preT};
  const float* whhs[2] = {enc_Whh, dec_Whh};
  unsigned step = 0;   // global step 1..510 across both phases

  for (int ph = 0; ph < 2; ++ph) {
    const float* pre = pres[ph];
    const float* Whh = whhs[ph];

    s16x8 afrag[16];
    {
      const float* wrow = Whh + (long)(ag * 500 + (auok ? au : 0)) * 500;
#pragma unroll
      for (int ch = 0; ch < 16; ++ch) {
        const int k0 = ch * 32 + kq * 8;
        float4 v0 = make_float4(0.f, 0.f, 0.f, 0.f);
        float4 v1 = make_float4(0.f, 0.f, 0.f, 0.f);
        if (auok && k0 < 500)     v0 = *(const float4*)(wrow + k0);
        if (auok && k0 + 4 < 500) v1 = *(const float4*)(wrow + k0 + 4);
        const u16x8 p = {f2b(v0.x), f2b(v0.y), f2b(v0.z), f2b(v0.w),
                         f2b(v1.x), f2b(v1.y), f2b(v1.z), f2b(v1.w)};
        afrag[ch] = (s16x8)p;
      }
    }

    for (int t = 0; t < 255; ++t) {
      ++step;
      const unsigned want = step - 1;
      const int buf = step & 1;
      const ull* rring = hring + (ull)((step - 1) % 3) * RING_SLOTS + gbase;
      ull* wring = hring + (ull)(step % 3) * RING_SLOTS + gbase;

      float pv[4];
#pragma unroll
      for (int g = 0; g < 4; ++g) pv[g] = pre[preoff[g] + t * 32];

      // poll-gather: slot s = tid + j*256 -> (u = s>>2, c = s&3); coalesced.
      // LDS write per-arrival so stragglers don't delay completed slots.
      unsigned pend = (tid < 208) ? 0xffu : 0x7fu;
      while (pend) {
        unsigned np = pend;
#pragma unroll
        for (int j = 0; j < 8; ++j) {
          if (np & (1u << j)) {
            const int s = tid + j * 256;
            const ull v = __hip_atomic_load(&rring[s], __ATOMIC_RELAXED,
                                            __HIP_MEMORY_SCOPE_AGENT);
            if ((unsigned)(v >> 32) >= want) {
              hb16[buf][(s & 3) * PITCH_H + (s >> 2)] =
                  f2b(__uint_as_float((unsigned)(v & 0xffffffffu)));
              np &= ~(1u << j);
            }
          }
        }
        pend = np;
        if (pend) __builtin_amdgcn_s_sleep(1);
      }
      __syncthreads();

      f32x4 acc = (f32x4){0.f, 0.f, 0.f, 0.f};
      const unsigned short* hbase = &hb16[buf][(c & 3) * PITCH_H + kq * 8];
#pragma unroll
      for (int ch = 0; ch < 16; ++ch) {
        const s16x8 bfrag = *(const s16x8*)(hbase + ch * 32);
        acc = __builtin_amdgcn_mfma_f32_16x16x32_bf16(afrag[ch], bfrag, acc,
                                                      0, 0, 0);
      }

      if (act) {
        const float iv = acc[0] + pv[0];
        const float fv = acc[1] + pv[1];
        const float gv = acc[2] + pv[2];
        const float ov = acc[3] + pv[3];
        const float cn = fsig(fv) * creg + fsig(iv) * ftanh(gv);
        const float hn = fsig(ov) * ftanh(cn);
        creg = cn;
        // publish value+tag in one atomic: the data IS the flag
        __hip_atomic_store(&wring[(uout << 2) + c],
                           ((ull)step << 32) | __float_as_uint(hn),
                           __ATOMIC_RELAXED, __HIP_MEMORY_SCOPE_AGENT);
        if (ph == 1)
          dec_h[(long)(t * 32 + b0 + c) * 500 + uout] = hn;
      }
    }
  }
}

// ---------------- per-row log-softmax NLL ----------------
__device__ __forceinline__ float wave_max(float v) {
#pragma unroll
  for (int o = 32; o > 0; o >>= 1) v = fmaxf(v, __shfl_xor(v, o, 64));
  return v;
}
__device__ __forceinline__ float wave_sum(float v) {
#pragma unroll
  for (int o = 32; o > 0; o >>= 1) v += __shfl_xor(v, o, 64);
  return v;
}

__global__ __launch_bounds__(256) void loss_rows(
    const float* __restrict__ seq, const float* __restrict__ logits,
    const int* __restrict__ nseq, float* __restrict__ nll) {
  __shared__ float sm[8];
  const int r = blockIdx.x, tid = threadIdx.x;
  const int t = r >> 5, b = r & 31;
  const float* row = (t == 0) ? (seq + (long)b * VV)
                              : (logits + (long)((t - 1) * 32 + b) * VV);
  float m = -INFINITY;
  for (int c = tid; c < 1178; c += 256) {
    float4 v = *(const float4*)&row[c * 4];
    m = fmaxf(m, fmaxf(fmaxf(v.x, v.y), fmaxf(v.z, v.w)));
  }
  m = wave_max(m);
  const int wid = tid >> 6;
  if ((tid & 63) == 0) sm[wid] = m;
  __syncthreads();
  const float M4 = fmaxf(fmaxf(sm[0], sm[1]), fmaxf(sm[2], sm[3]));
  float s = 0.0f;
  for (int c = tid; c < 1178; c += 256) {
    float4 v = *(const float4*)&row[c * 4];
    s += expf(v.x - M4) + expf(v.y - M4) + expf(v.z - M4) + expf(v.w - M4);
  }
  s = wave_sum(s);
  if ((tid & 63) == 0) sm[4 + wid] = s;
  __syncthreads();
  if (tid == 0) {
    const float S = sm[4] + sm[5] + sm[6] + sm[7];
    const int tgt = nseq[(t << 5) + b];
    nll[r] = M4 + logf(S) - row[tgt];
  }
}

__global__ __launch_bounds__(256) void final_reduce(
    const float* __restrict__ nll, float* __restrict__ out) {
  __shared__ float sm[4];
  float s = 0.0f;
  for (int c = threadIdx.x; c < 8192; c += 256) s += nll[c];
  s = wave_sum(s);
  if ((threadIdx.x & 63) == 0) sm[threadIdx.x >> 6] = s;
  __syncthreads();
  if (threadIdx.x == 0) out[0] = (sm[0] + sm[1] + sm[2] + sm[3]) * (1.0f / 8192.0f);
}

// ---------------- launch ----------------
extern "C" void kernel_launch(void* const* d_in, const int* in_sizes, int n_in,
                              void* d_out, int out_size, void* d_ws, size_t ws_size,
                              hipStream_t stream) {
  (void)in_sizes; (void)n_in; (void)out_size; (void)ws_size;
  const float* seq  = (const float*)d_in[0];
  const int* nseq   = (const int*)d_in[1];
  const float* eWih = (const float*)d_in[2];
  const float* eWhh = (const float*)d_in[3];
  const float* ebih = (const float*)d_in[4];
  const float* ebhh = (const float*)d_in[5];
  const float* dWih = (const float*)d_in[6];
  const float* dWhh = (const float*)d_in[7];
  const float* dbih = (const float*)d_in[8];
  const float* dbhh = (const float*)d_in[9];
  const float* oW   = (const float*)d_in[10];
  const float* ob   = (const float*)d_in[11];

  float* wsf = (float*)d_ws;
  float* logits   = wsf;
  float* enc_preT = wsf;
  float* dec_preT = wsf + OFF_DECPRE;
  ull*   hring    = (ull*)(wsf + OFF_HR);
  float* dec_h    = wsf + OFF_DECH;
  float* nll      = wsf + OFF_NLL;

  // rings: {f32 0.0 | tag 0} everywhere; ring0 tag0 == initial h^0 (want=0)
  hipMemsetAsync(hring, 0, 3 * RING_SLOTS * sizeof(ull), stream);

  // enc_preT[j][t*32+b] = eWih[j,:] . seq[(255-t)*32+b,:] + ebih[j]+ebhh[j]
  gemm_bf16_256<<<dim3(256), dim3(512), 0, stream>>>(
      eWih, VV, seq, VV, 1, 1, ebih, ebhh,
      enc_preT, MPRE, FOURH, MPRE, VV, 32, 1);
  // dec_preT[j][t*32+b] = dWih[j,:] . seq[t*32+b,:] + dbih[j]+dbhh[j]
  gemm_bf16_256<<<dim3(256), dim3(512), 0, stream>>>(
      dWih, VV, seq, VV, 0, 1, dbih, dbhh,
      dec_preT, MPRE, FOURH, MPRE, VV, 32, 1);
  // recurrence (encoder then decoder), writes dec_h
  lstm_rec<<<dim3(256), dim3(256), 0, stream>>>(enc_preT, dec_preT, eWhh, dWhh,
                                                hring, dec_h);
  // logits = dec_h @ out_W^T + out_b  (32 mtiles x 19 ntiles = 608 blocks)
  gemm_bf16_256<<<dim3(608), dim3(512), 0, stream>>>(
      dec_h, HH, oW, HH, 0, 0, ob, nullptr,
      logits, VV, MPRE, VV, HH, 19, 0);
  // per-row NLL then deterministic reduce
  loss_rows<<<dim3(8192), dim3(256), 0, stream>>>(seq, logits, nseq, nll);
  final_reduce<<<dim3(1), dim3(256), 0, stream>>>(nll, (float*)d_out);
}